// Round 9
// baseline (813.030 us; speedup 1.0000x reference)
//
#include <hip/hip_runtime.h>
#include <hip/hip_bf16.h>
#include <math.h>

// LiquidNCA via bf16 MFMA, v3.13 = v3.12 (708 us) + stage-C LDS-pipe relief.
// Pipe audit at R8: LDS pipe ~75% busy (the max pipe; one LDS unit per CU
// serving 4 SIMDs), VALU 64%, MFMA 21%, HBM 15%. Lever = LDS instr count.
// New in v3.13:
//  (1) su (own core pixel state) and x8c (tau tap-8 x) stage-C reads moved
//      from LDS to entry-time GLOBAL prefetch (R1-proven tpre pattern): both
//      are verbatim copies of stIn[pix] / xp8g[...] with addresses known at
//      kernel entry; latency hides under stages A+B and two barriers.
//      Deletes 8 LDS wave-instrs (4 b64 + 4 u16) ~= 10% of LDS pipe load,
//      bit-identically. du stays in LDS (cross-lane delta exchange; verified
//      no lane self-produces its core pixel's delta).
//  (2) beta clamp via __builtin_amdgcn_fmed3f (1 VALU op vs 2; identical
//      result for the finite positive bta).
// v3.12 carried: ZERO-SHUFFLE up2 (k-slot-remapped wu2f; lane's own hv is
// its B-fragment -- no bpermute), stage-C tap-row register cache, stage-B
// tap-8 folded into 5th MFMA at K=24, interior-block fast path, incremental
// py/px, setprio around conv MFMA clusters, RHU pack, tau x via 10th stage-C
// MFMA, no tx tensor (163 MB working set fits L3), LDS = comb only 32000 B.
// Core concept (R14-verified): mfma(weights, pixels, acc) -> D[channel][pixel]
// (A/B lane layouts are identical), so each lane owns 1 pixel x 4 consecutive
// channels and every epilogue access is one aligned b64.

#define B_   32
#define H_   256
#define W_   256
#define PIT  40                // comb pitch in ushorts (80 B, 16B-aligned)
#define XPP  260               // xp8pad padded dim (base gy in [-2, 257])

typedef unsigned short ushort_t;
typedef __attribute__((ext_vector_type(8))) short short8;
typedef __attribute__((ext_vector_type(4))) float float4v;

__device__ __forceinline__ unsigned fbits(float f) {
    union { float f; unsigned u; } v; v.f = f; return v.u;
}
__device__ __forceinline__ ushort_t f2bu(float f) {        // finite-only, RHU
    return (ushort_t)((fbits(f) + 0x8000u) >> 16);
}
__device__ __forceinline__ unsigned pack2(float lo, float hi) {
    return ((fbits(hi) + 0x8000u) & 0xFFFF0000u) | ((fbits(lo) + 0x8000u) >> 16);
}
__device__ __forceinline__ float bu2f(ushort_t u) {
    union { unsigned i; float f; } v; v.i = ((unsigned)u) << 16; return v.f;
}
__device__ __forceinline__ float lo2f(unsigned u) {
    union { unsigned i; float f; } v; v.i = u << 16; return v.f;
}
__device__ __forceinline__ float hi2f(unsigned u) {
    union { unsigned i; float f; } v; v.i = u & 0xFFFF0000u; return v.f;
}

// ---------------------------------------------------------------------------
// prep: UNCHANGED from v3.12.
__global__ void prep(
    const float* __restrict__ wp,   // [32][17][9]
    const float* __restrict__ wu1,  // [16][32]
    const float* __restrict__ bu1,  // [16]
    const float* __restrict__ bp,   // [32]
    const float* __restrict__ wu2,  // [16][16]
    const float* __restrict__ wt,   // [16][33][9]
    const float* __restrict__ btc,  // [16]
    const float* __restrict__ bt,   // [16]
    ushort_t* __restrict__ wh1p,    // [5][64][8]  4 pairs + (tap8||x0..8)
    ushort_t* __restrict__ wu2f,    // [64][8]
    ushort_t* __restrict__ wtxf,    // [64][8]  tau x-taps, K: 0..7 used
    ushort_t* __restrict__ wtn,     // [9][64][8]
    float* __restrict__ scal)       // [64] beff | wxh8 | tb | wtx8
{
    __shared__ float Weff[16 * 153];   // [n][c(0..16)][t]
    const int tid = threadIdx.x;

    for (int i = tid; i < 16 * 153; i += 256) {
        int j = i / 153, rem = i % 153, c = rem / 9, t = rem % 9;
        float s = 0.f;
        for (int o = 0; o < 32; ++o)
            s += wu1[j * 32 + o] * wp[o * 153 + c * 9 + t];
        Weff[i] = s;
    }
    if (tid < 16) {
        float s = bu1[tid];
        for (int o = 0; o < 32; ++o) s += wu1[tid * 32 + o] * bp[o];
        scal[tid] = s;                          // beff
    }
    if (tid < 16) scal[32 + tid] = btc[tid] + bt[tid];   // tau bias
    if (tid < 16) scal[48 + tid] = wt[tid * 297 + 8];    // tau tap-8 x weight
    __syncthreads();

    if (tid < 16) scal[16 + tid] = Weff[tid * 153 + 8];   // wxh8 (c=0, tap8)

    // pairs ii=0..3: K = [state@tap2ii (k0..15) || state@tap2ii+1 (k16..31)]
    for (int i = tid; i < 4 * 64 * 8; i += 256) {
        int ii = i >> 9, lane = (i >> 3) & 63, j = i & 7;
        int n = lane & 15, kk = ((lane >> 4) << 3) + j;
        int tap = 2 * ii + (kk >> 4), ch = kk & 15;
        wh1p[i] = f2bu(Weff[n * 153 + (ch + 1) * 9 + tap]);
    }
    // 5th: k<16 -> state@tap8; k=16..23 -> x@tap(k-16); k==24 -> x@tap8; else 0
    for (int i = tid; i < 512; i += 256) {
        int lane = i >> 3, j = i & 7;
        int n = lane & 15, k = ((lane >> 4) << 3) + j;
        float v = 0.f;
        if (k < 16)       v = Weff[n * 153 + (k + 1) * 9 + 8];
        else if (k < 24)  v = Weff[n * 153 + (k - 16)];      // c=0, tap k-16
        else if (k == 24) v = Weff[n * 153 + 8];             // c=0, tap 8
        wh1p[2048 + i] = f2bu(v);
    }
    // wu2f (zero-shuffle remap): k = 8a+b -> (b<4) ? wu2[n][4a+b] : 0
    for (int i = tid; i < 512; i += 256) {
        int lane = i >> 3, j = i & 7;
        int n = lane & 15, k = ((lane >> 4) << 3) + j;
        int a = k >> 3, b = k & 7;
        wu2f[i] = (b < 4) ? f2bu(wu2[n * 16 + 4 * a + b]) : (ushort_t)0;
    }
    // wtxf: tau x-tap weights wt[n][0][t], K-slot t = tap (0..7), else 0
    for (int i = tid; i < 512; i += 256) {
        int lane = i >> 3, j = i & 7;
        int n = lane & 15, k = ((lane >> 4) << 3) + j;
        wtxf[i] = (k < 8) ? f2bu(wt[n * 297 + k]) : (ushort_t)0;
    }
    // wtn: A = [delta(16) || state(16)] weights for tau
    for (int i = tid; i < 9 * 64 * 8; i += 256) {
        int t = i / 512, lane = (i / 8) % 64, j = i % 8;
        int n = lane & 15, k = ((lane >> 4) << 3) + j;
        int c = (k < 16) ? (17 + k) : (k - 15);
        wtn[i] = f2bu(wt[n * 297 + c * 9 + t]);
    }
}

// ---------------------------------------------------------------------------
// xp8pad[b][by][bx][8] = bf16 x at taps 0..7 of the 3x3 window based at
// global (by-2, bx-2); out-of-image taps are zero. tap0 = own x.
__global__ __launch_bounds__(256) void precompute_xp8(
    const float* __restrict__ x,     // [B][H][W] fp32
    ushort_t* __restrict__ xp8)      // [B][XPP][XPP][8] bf16
{
    int idx = blockIdx.x * 256 + threadIdx.x;
    if (idx >= B_ * XPP * XPP) return;
    int b  = idx / (XPP * XPP), rem = idx - b * (XPP * XPP);
    int by = rem / XPP, bx = rem - by * XPP;
    int gy = by - 2, gx = bx - 2;                 // window base in image coords
    const float* xb = x + (size_t)b * 65536;
    short8 v;
#pragma unroll
    for (int t = 0; t < 8; ++t) {
        int yy = gy + t / 3, xx = gx + t % 3;
        bool in = ((unsigned)yy < 256u) & ((unsigned)xx < 256u);
        v[t] = in ? (short)f2bu(xb[yy * 256 + xx]) : (short)0;
    }
    *(short8*)(xp8 + (size_t)idx * 8) = v;
}

// ---------------------------------------------------------------------------
__global__ __launch_bounds__(256) void nca_step(
    const ushort_t* __restrict__ stIn,   // [B][H][W][16] bf16 (unused if first)
    ushort_t* __restrict__ stOut,        // [B][H][W][16] bf16 (unused if last)
    const ushort_t* __restrict__ xp8g,   // [B][XPP][XPP][8] bf16
    const ushort_t* __restrict__ wh1p,
    const ushort_t* __restrict__ wu2f,
    const ushort_t* __restrict__ wtxf,
    const ushort_t* __restrict__ wtn,
    const float* __restrict__ scal,      // [64] beff | wxh8 | tb | wtx8
    const float* __restrict__ bu2G,
    const float* __restrict__ wrd,       // w_read [16]
    const float* __restrict__ brd,       // b_read [1]
    float* __restrict__ outg,            // [B][H][W] fp32 (used if last)
    int first, int last)
{
    __shared__ ushort_t comb[400 * PIT]; // 20x20 halo-2; LDS = 32000 B

    const int tid  = threadIdx.x;
    const int w    = tid >> 6, lane = tid & 63;
    const int m    = lane & 15, q = lane >> 4;
    const int och  = q * 4;              // base out-channel of this lane's D rows
    const int gx0  = blockIdx.x * 16, gy0 = blockIdx.y * 16;
    const size_t pb = (size_t)blockIdx.z * 65536;
    const size_t xpb = (size_t)blockIdx.z * (XPP * XPP);
    const short8 z8 = {0, 0, 0, 0, 0, 0, 0, 0};
    const float4v z4 = {0.f, 0.f, 0.f, 0.f};

    // all staged rows / h1 pixels / delta pixels in-image for this block?
    const bool interior = (blockIdx.x >= 1) & (blockIdx.x <= 14)
                        & (blockIdx.y >= 1) & (blockIdx.y <= 14);

    // ---- entry prefetch (stage-C su / x8c; addresses known now; latency ----
    // ---- hides under stages A+B and two barriers). Bit-identical data:  ----
    // ---- stage A would copy these exact bytes into comb.                ----
    uint2    spre[4];
    ushort_t xpre[4];
#pragma unroll
    for (int i = 0; i < 4; ++i) {
        const size_t pix = pb + (size_t)(gy0 + w * 4 + i) * 256 + gx0 + m;
        if (!first) spre[i] = *(const uint2*)(stIn + pix * 16 + och);
        else        { spre[i].x = 0u; spre[i].y = 0u; }
        xpre[i] = xp8g[(xpb + (size_t)(gy0 + w * 4 + i + 3) * XPP
                        + (gx0 + m + 3)) * 8];
    }

    // per-wave weight fragments (used as MFMA *A* operands)
    short8 wh1r[5], wtnr[9];
#pragma unroll
    for (int i = 0; i < 5; ++i) wh1r[i] = *(const short8*)(wh1p + (i * 64 + lane) * 8);
#pragma unroll
    for (int t = 0; t < 9; ++t) wtnr[t] = *(const short8*)(wtn + (t * 64 + lane) * 8);
    const short8 wu2r = *(const short8*)(wu2f + lane * 8);
    const short8 wtxr = *(const short8*)(wtxf + lane * 8);

    // per-lane channel-quad biases (channels och..och+3)
    float4v beff4, bu24, wr4, tb4, wtx84;
#pragma unroll
    for (int r = 0; r < 4; ++r) {
        beff4[r] = scal[och + r];
        tb4[r]   = scal[32 + och + r];
        wtx84[r] = scal[48 + och + r];
        bu24[r]  = bu2G[och + r];
        wr4[r]   = wrd[och + r];
    }
    const float br = brd[0];

    // per-lane paired-tap B-read offsets (tap = 2*ii + (q>>1))
    const int sel = q >> 1;
    int offp[4];
#pragma unroll
    for (int ii = 0; ii < 4; ++ii) {
        int tA = 2 * ii, tB = 2 * ii + 1;
        int oA = ((tA / 3) * 20 + (tA % 3)) * PIT;
        int oB = ((tB / 3) * 20 + (tB % 3)) * PIT;
        offp[ii] = sel ? oB : oA;
    }
    const int chOff = 16 + (q & 1) * 8;
    const int t8off = (2 * 20 + 2) * PIT;
    // 5th-MFMA B offsets: q=0/1 -> state@tap8 (k0..15); q=2 -> x taps0..7
    // (k16..23); q=3 -> chunk4 of row (py+2,px+2): j=0 = x@tap8 (k24).
    const int off5  = (q == 0) ? (t8off + 16) : (q == 1) ? (t8off + 24)
                    : (q == 2) ? 32 : (t8off + 32);

    // ---- stage A: stage state ch16..31 + xpatch8 ch32..39 (coalesced) ------
    if (interior & (first == 0)) {
        for (int p = tid; p < 400; p += 256) {
            int ry = p / 20, rx = p - ry * 20;
            ushort_t* row = comb + p * PIT;
            const ushort_t* sp = stIn
                + (pb + (size_t)(gy0 + ry - 2) * 256 + (gx0 + rx - 2)) * 16;
            *(short8*)(row + 16) = *(const short8*)(sp);
            *(short8*)(row + 24) = *(const short8*)(sp + 8);
            *(short8*)(row + 32) = *(const short8*)(
                xp8g + (xpb + (size_t)(gy0 + ry) * XPP + (gx0 + rx)) * 8);
        }
    } else {
        for (int p = tid; p < 400; p += 256) {
            int ry = p / 20, rx = p - ry * 20;
            int gy = gy0 + ry - 2, gx = gx0 + rx - 2;
            ushort_t* row = comb + p * PIT;
            bool in = ((unsigned)gy < 256u) & ((unsigned)gx < 256u);
            if (in && !first) {
                const ushort_t* sp = stIn + (pb + gy * 256 + gx) * 16;
                *(short8*)(row + 16) = *(const short8*)(sp);
                *(short8*)(row + 24) = *(const short8*)(sp + 8);
            } else {
                *(short8*)(row + 16) = z8; *(short8*)(row + 24) = z8;
            }
            *(short8*)(row + 32) = *(const short8*)(
                xp8g + (xpb + (size_t)(gy0 + ry) * XPP + (gx0 + rx)) * 8);
        }
    }
    __syncthreads();

    // ---- stage B: 5-MFMA h1 conv (D[ch][pix]) -> up2 -> inline delta -------
    {
        int raw = w * 16 + m;                    // pixel index for i=0
        int py = raw / 18, px = raw - (raw / 18) * 18;
        for (int i = 0; i < 6; ++i) {
            int g = w + 4 * i; if (g >= 21) break;
            bool vld = raw < 324;
            int pyc = vld ? py : 17, pxc = vld ? px : 17;
            const ushort_t* abase = comb + (pyc * 20 + pxc) * PIT;
            float4v acc = z4;
            __builtin_amdgcn_s_setprio(1);
#pragma unroll
            for (int ii = 0; ii < 4; ++ii) {
                short8 b = *(const short8*)(abase + offp[ii] + chOff);
                acc = __builtin_amdgcn_mfma_f32_16x16x32_bf16(wh1r[ii], b, acc, 0, 0, 0);
            }
            {   // 5th: [state@tap8 || x@taps0..7 || x@tap8 || 0]
                short8 b = *(const short8*)(abase + off5);
                acc = __builtin_amdgcn_mfma_f32_16x16x32_bf16(wh1r[4], b, acc, 0, 0, 0);
            }
            __builtin_amdgcn_s_setprio(0);
            // epilogue: this lane owns pixel (pyc,pxc), channels och..och+3
            uint2 hv;
            {
                float h0 = fmaxf(acc[0] + beff4[0], 0.f);
                float h1 = fmaxf(acc[1] + beff4[1], 0.f);
                float h2 = fmaxf(acc[2] + beff4[2], 0.f);
                float h3 = fmaxf(acc[3] + beff4[3], 0.f);
                hv.x = pack2(h0, h1); hv.y = pack2(h2, h3);
            }
            // ZERO-SHUFFLE up2: lane (m,q) supplies B k-slots 8q..8q+7; wu2f
            // places channel 4q+jj at k-slot 8q+jj (jj<4) and 0 at jj>=4, so
            // this lane's own hv IS its B-fragment. Each channel is summed
            // exactly once (from the lane that computed it). No bpermute.
            union { unsigned u4[4]; short8 s8; } bb;
            bb.u4[0] = hv.x; bb.u4[1] = hv.y; bb.u4[2] = 0u; bb.u4[3] = 0u;
            float4v d = __builtin_amdgcn_mfma_f32_16x16x32_bf16(wu2r, bb.s8, z4, 0, 0, 0);
            // delta: pixel (pyc,pxc), channels och..och+3 -> one b64 write
            uint2 dv;
            dv.x = pack2(d[0] + bu24[0], d[1] + bu24[1]);
            dv.y = pack2(d[2] + bu24[2], d[3] + bu24[3]);
            if (!interior) {
                int gy = gy0 - 1 + pyc, gx = gx0 - 1 + pxc;
                bool im = ((unsigned)gy < 256u) & ((unsigned)gx < 256u);
                if (!im) { dv.x = 0u; dv.y = 0u; }   // ref zero-pads outside
            }
            if (vld)
                *(uint2*)(comb + ((pyc + 1) * 20 + (pxc + 1)) * PIT + och) = dv;
            // increment pixel index by 64: +3 rows +10 cols (mod 18)
            raw += 64; px += 10; py += 3;
            if (px >= 18) { px -= 18; py += 1; }
        }
    }
    __syncthreads();

    // ---- stage C: tau conv (D[ch][pix], K=32 [delta||state]) + x via MFMA --
    // Tap-row register cache: Ta = row g+1, Tb = row g+2 (dx = 0..2, chunk q);
    // per iteration load only the fresh row g+3, then rotate. su/x8c come
    // from the entry prefetch (spre/xpre), not LDS.
    {
        const int w4 = w * 4;
#define LDROW(r, dx) (*(const short8*)(comb + (((r) * 20) + (m + 1 + (dx))) * PIT + q * 8))
        short8 Ta0 = LDROW(w4 + 1, 0), Ta1 = LDROW(w4 + 1, 1), Ta2 = LDROW(w4 + 1, 2);
        short8 Tb0 = LDROW(w4 + 2, 0), Tb1 = LDROW(w4 + 2, 1), Tb2 = LDROW(w4 + 2, 2);
#pragma unroll
        for (int i = 0; i < 4; ++i) {
            int g = w4 + i;                      // core row; pixel col = m
            short8 Tc0 = LDROW(g + 3, 0), Tc1 = LDROW(g + 3, 1), Tc2 = LDROW(g + 3, 2);
            // xp taps 0..7 for the 10th MFMA (window base = core-(1,1))
            short8 bx = *(const short8*)(comb + ((g + 1) * 20 + (m + 1)) * PIT + 32);
            float4v acc = z4;
            __builtin_amdgcn_s_setprio(1);
            acc = __builtin_amdgcn_mfma_f32_16x16x32_bf16(wtnr[0], Ta0, acc, 0, 0, 0);
            acc = __builtin_amdgcn_mfma_f32_16x16x32_bf16(wtnr[1], Ta1, acc, 0, 0, 0);
            acc = __builtin_amdgcn_mfma_f32_16x16x32_bf16(wtnr[2], Ta2, acc, 0, 0, 0);
            acc = __builtin_amdgcn_mfma_f32_16x16x32_bf16(wtnr[3], Tb0, acc, 0, 0, 0);
            acc = __builtin_amdgcn_mfma_f32_16x16x32_bf16(wtnr[4], Tb1, acc, 0, 0, 0);
            acc = __builtin_amdgcn_mfma_f32_16x16x32_bf16(wtnr[5], Tb2, acc, 0, 0, 0);
            acc = __builtin_amdgcn_mfma_f32_16x16x32_bf16(wtnr[6], Tc0, acc, 0, 0, 0);
            acc = __builtin_amdgcn_mfma_f32_16x16x32_bf16(wtnr[7], Tc1, acc, 0, 0, 0);
            acc = __builtin_amdgcn_mfma_f32_16x16x32_bf16(wtnr[8], Tc2, acc, 0, 0, 0);
            acc = __builtin_amdgcn_mfma_f32_16x16x32_bf16(wtxr,   bx,  acc, 0, 0, 0);
            __builtin_amdgcn_s_setprio(0);
            int gy = gy0 + g;
            const size_t pix = pb + gy * 256 + gx0 + m;
            const ushort_t* cpx = comb + ((g + 2) * 20 + (m + 2)) * PIT;
            float x8c = bu2f(xpre[i]);                         // prefetched
            uint2 su = spre[i];                                // prefetched
            uint2 du = *(const uint2*)(cpx + och);             // delta (LDS)
            float sold[4] = { lo2f(su.x), hi2f(su.x), lo2f(su.y), hi2f(su.y) };
            float dvv[4]  = { lo2f(du.x), hi2f(du.x), lo2f(du.y), hi2f(du.y) };
            float sn[4];
#pragma unroll
            for (int r = 0; r < 4; ++r) {
                float tl  = acc[r] + tb4[r] + x8c * wtx84[r];
                float e   = __expf(-tl);
                float bta = __builtin_amdgcn_rcpf(1.f + e);
                bta = __builtin_amdgcn_fmed3f(bta, 0.01f, 0.99f);
                sn[r] = dvv[r] + bta * (sold[r] - dvv[r]);
            }
            if (!last) {
                uint2 o;
                o.x = pack2(sn[0], sn[1]); o.y = pack2(sn[2], sn[3]);
                *(uint2*)(stOut + pix * 16 + och) = o;         // b64 store
            } else {
                // fused readout: channels spread over q -> butterfly on q bits
                float v = sn[0] * wr4[0] + sn[1] * wr4[1]
                        + sn[2] * wr4[2] + sn[3] * wr4[3];
                v += __shfl_xor(v, 16);
                v += __shfl_xor(v, 32);
                if (q == 0) {
                    float eo = __expf(-(v + br));
                    outg[pix] = __builtin_amdgcn_rcpf(1.f + eo);
                }
            }
            // rotate the row cache
            Ta0 = Tb0; Ta1 = Tb1; Ta2 = Tb2;
            Tb0 = Tc0; Tb1 = Tc1; Tb2 = Tc2;
        }
#undef LDROW
    }
}

// ---------------------------------------------------------------------------
extern "C" void kernel_launch(void* const* d_in, const int* in_sizes, int n_in,
                              void* d_out, int out_size, void* d_ws, size_t ws_size,
                              hipStream_t stream)
{
    const float* x          = (const float*)d_in[0];
    const float* w_perceive = (const float*)d_in[1];
    const float* b_perceive = (const float*)d_in[2];
    const float* w_up1      = (const float*)d_in[3];
    const float* b_up1      = (const float*)d_in[4];
    const float* w_up2      = (const float*)d_in[5];
    const float* b_up2      = (const float*)d_in[6];
    const float* w_tau      = (const float*)d_in[7];
    const float* b_tau_conv = (const float*)d_in[8];
    const float* b_tau      = (const float*)d_in[9];
    const float* w_read     = (const float*)d_in[10];
    const float* b_read     = (const float*)d_in[11];
    // d_in[12] = n_steps = 10 (host-known; hard-coded for graph capture)
    float* out = (float*)d_out;

    const size_t stateElems = (size_t)B_ * H_ * W_ * 16;     // 33,554,432 bf16
    const size_t xp8Elems   = (size_t)B_ * XPP * XPP * 8;    // 17,305,600 bf16

    // ws layout (~170 MB; tx tensor deleted)
    ushort_t* stA  = (ushort_t*)d_ws;
    ushort_t* stB  = stA + stateElems;
    ushort_t* xp8g = stB + stateElems;         // 34.6 MB
    ushort_t* wh1p = xp8g + xp8Elems;          // 2560
    ushort_t* wu2f = wh1p + 2560;              // 512
    ushort_t* wtxf = wu2f + 512;               // 512
    ushort_t* wtn  = wtxf + 512;               // 4608
    float*    scal = (float*)(wtn + 4608);     // 64 floats

    const size_t needBytes = (2 * stateElems + xp8Elems
                              + 2560 + 512 + 512 + 4608) * sizeof(ushort_t)
                           + 64 * sizeof(float);
    if (ws_size < needBytes) return;

    prep<<<dim3(1), dim3(256), 0, stream>>>(
        w_perceive, w_up1, b_up1, b_perceive, w_up2, w_tau,
        b_tau_conv, b_tau, wh1p, wu2f, wtxf, wtn, scal);
    precompute_xp8<<<dim3((B_ * XPP * XPP + 255) / 256), dim3(256), 0, stream>>>(
        x, xp8g);

    ushort_t* cur = stA;
    ushort_t* nxt = stB;
    for (int s = 0; s < 10; ++s) {
        nca_step<<<dim3(16, 16, 32), dim3(256), 0, stream>>>(
            cur, nxt, xp8g, wh1p, wu2f, wtxf, wtn, scal, b_up2,
            w_read, b_read, out, (s == 0) ? 1 : 0, (s == 9) ? 1 : 0);
        ushort_t* t = cur; cur = nxt; nxt = t;
    }
}

// Round 10
// 707.913 us; speedup vs baseline: 1.1485x; 1.1485x over previous
//
#include <hip/hip_runtime.h>
#include <hip/hip_bf16.h>
#include <math.h>

// LiquidNCA via bf16 MFMA, v3.14 = v3.12 (708 us best) + fmed3 clamp only.
// R9's stage-C global-prefetch REVERTED: it dropped bank conflicts as
// predicted (9.9e6 -> 8.6e6) but cost 15 us/step -- the entry prefetch's
// long-lived VMEM results + uncoalesced 2B xpre gathers made the kernel more
// stall-bound (occupancy 37 -> 30%), and both barriers already drain
// vmcnt(0), so nothing was hidden. su/x8c return to LDS reads.
// Kept from R9: beta clamp via __builtin_amdgcn_fmed3f (1 VALU op vs 2;
// bit-identical for the finite positive bta).
// v3.12 carried: ZERO-SHUFFLE up2 (k-slot-remapped wu2f: in mfma(A,B) a
// k-permutation applied to both operands is identity, so lane (m,q)'s own
// hv is its B-fragment -- no bpermute), stage-C tap-row register cache,
// stage-B tap-8 folded into 5th MFMA at K=24, interior-block fast path,
// incremental py/px, setprio around conv MFMA clusters, RHU pack, tau x via
// 10th stage-C MFMA, no tx tensor (163 MB working set fits L3), LDS = comb
// only 32000 B.
// LDS bank audit (R8/R9): all b128/b64 accesses sit at the wave64 structural
// minimum (8 bank-quad starts tiling 32 banks) -- no further conflict fix
// exists without a full layout overhaul.
// Core concept (R14-verified): mfma(weights, pixels, acc) -> D[channel][pixel]
// (A/B lane layouts are identical), so each lane owns 1 pixel x 4 consecutive
// channels and every epilogue access is one aligned b64.

#define B_   32
#define H_   256
#define W_   256
#define PIT  40                // comb pitch in ushorts (80 B, 16B-aligned)
#define XPP  260               // xp8pad padded dim (base gy in [-2, 257])

typedef unsigned short ushort_t;
typedef __attribute__((ext_vector_type(8))) short short8;
typedef __attribute__((ext_vector_type(4))) float float4v;

__device__ __forceinline__ unsigned fbits(float f) {
    union { float f; unsigned u; } v; v.f = f; return v.u;
}
__device__ __forceinline__ ushort_t f2bu(float f) {        // finite-only, RHU
    return (ushort_t)((fbits(f) + 0x8000u) >> 16);
}
__device__ __forceinline__ unsigned pack2(float lo, float hi) {
    return ((fbits(hi) + 0x8000u) & 0xFFFF0000u) | ((fbits(lo) + 0x8000u) >> 16);
}
__device__ __forceinline__ float bu2f(ushort_t u) {
    union { unsigned i; float f; } v; v.i = ((unsigned)u) << 16; return v.f;
}
__device__ __forceinline__ float lo2f(unsigned u) {
    union { unsigned i; float f; } v; v.i = u << 16; return v.f;
}
__device__ __forceinline__ float hi2f(unsigned u) {
    union { unsigned i; float f; } v; v.i = u & 0xFFFF0000u; return v.f;
}

// ---------------------------------------------------------------------------
// prep: UNCHANGED from v3.12.
__global__ void prep(
    const float* __restrict__ wp,   // [32][17][9]
    const float* __restrict__ wu1,  // [16][32]
    const float* __restrict__ bu1,  // [16]
    const float* __restrict__ bp,   // [32]
    const float* __restrict__ wu2,  // [16][16]
    const float* __restrict__ wt,   // [16][33][9]
    const float* __restrict__ btc,  // [16]
    const float* __restrict__ bt,   // [16]
    ushort_t* __restrict__ wh1p,    // [5][64][8]  4 pairs + (tap8||x0..8)
    ushort_t* __restrict__ wu2f,    // [64][8]
    ushort_t* __restrict__ wtxf,    // [64][8]  tau x-taps, K: 0..7 used
    ushort_t* __restrict__ wtn,     // [9][64][8]
    float* __restrict__ scal)       // [64] beff | wxh8 | tb | wtx8
{
    __shared__ float Weff[16 * 153];   // [n][c(0..16)][t]
    const int tid = threadIdx.x;

    for (int i = tid; i < 16 * 153; i += 256) {
        int j = i / 153, rem = i % 153, c = rem / 9, t = rem % 9;
        float s = 0.f;
        for (int o = 0; o < 32; ++o)
            s += wu1[j * 32 + o] * wp[o * 153 + c * 9 + t];
        Weff[i] = s;
    }
    if (tid < 16) {
        float s = bu1[tid];
        for (int o = 0; o < 32; ++o) s += wu1[tid * 32 + o] * bp[o];
        scal[tid] = s;                          // beff
    }
    if (tid < 16) scal[32 + tid] = btc[tid] + bt[tid];   // tau bias
    if (tid < 16) scal[48 + tid] = wt[tid * 297 + 8];    // tau tap-8 x weight
    __syncthreads();

    if (tid < 16) scal[16 + tid] = Weff[tid * 153 + 8];   // wxh8 (c=0, tap8)

    // pairs ii=0..3: K = [state@tap2ii (k0..15) || state@tap2ii+1 (k16..31)]
    for (int i = tid; i < 4 * 64 * 8; i += 256) {
        int ii = i >> 9, lane = (i >> 3) & 63, j = i & 7;
        int n = lane & 15, kk = ((lane >> 4) << 3) + j;
        int tap = 2 * ii + (kk >> 4), ch = kk & 15;
        wh1p[i] = f2bu(Weff[n * 153 + (ch + 1) * 9 + tap]);
    }
    // 5th: k<16 -> state@tap8; k=16..23 -> x@tap(k-16); k==24 -> x@tap8; else 0
    for (int i = tid; i < 512; i += 256) {
        int lane = i >> 3, j = i & 7;
        int n = lane & 15, k = ((lane >> 4) << 3) + j;
        float v = 0.f;
        if (k < 16)       v = Weff[n * 153 + (k + 1) * 9 + 8];
        else if (k < 24)  v = Weff[n * 153 + (k - 16)];      // c=0, tap k-16
        else if (k == 24) v = Weff[n * 153 + 8];             // c=0, tap 8
        wh1p[2048 + i] = f2bu(v);
    }
    // wu2f (zero-shuffle remap): k = 8a+b -> (b<4) ? wu2[n][4a+b] : 0
    for (int i = tid; i < 512; i += 256) {
        int lane = i >> 3, j = i & 7;
        int n = lane & 15, k = ((lane >> 4) << 3) + j;
        int a = k >> 3, b = k & 7;
        wu2f[i] = (b < 4) ? f2bu(wu2[n * 16 + 4 * a + b]) : (ushort_t)0;
    }
    // wtxf: tau x-tap weights wt[n][0][t], K-slot t = tap (0..7), else 0
    for (int i = tid; i < 512; i += 256) {
        int lane = i >> 3, j = i & 7;
        int n = lane & 15, k = ((lane >> 4) << 3) + j;
        wtxf[i] = (k < 8) ? f2bu(wt[n * 297 + k]) : (ushort_t)0;
    }
    // wtn: A = [delta(16) || state(16)] weights for tau
    for (int i = tid; i < 9 * 64 * 8; i += 256) {
        int t = i / 512, lane = (i / 8) % 64, j = i % 8;
        int n = lane & 15, k = ((lane >> 4) << 3) + j;
        int c = (k < 16) ? (17 + k) : (k - 15);
        wtn[i] = f2bu(wt[n * 297 + c * 9 + t]);
    }
}

// ---------------------------------------------------------------------------
// xp8pad[b][by][bx][8] = bf16 x at taps 0..7 of the 3x3 window based at
// global (by-2, bx-2); out-of-image taps are zero. tap0 = own x.
__global__ __launch_bounds__(256) void precompute_xp8(
    const float* __restrict__ x,     // [B][H][W] fp32
    ushort_t* __restrict__ xp8)      // [B][XPP][XPP][8] bf16
{
    int idx = blockIdx.x * 256 + threadIdx.x;
    if (idx >= B_ * XPP * XPP) return;
    int b  = idx / (XPP * XPP), rem = idx - b * (XPP * XPP);
    int by = rem / XPP, bx = rem - by * XPP;
    int gy = by - 2, gx = bx - 2;                 // window base in image coords
    const float* xb = x + (size_t)b * 65536;
    short8 v;
#pragma unroll
    for (int t = 0; t < 8; ++t) {
        int yy = gy + t / 3, xx = gx + t % 3;
        bool in = ((unsigned)yy < 256u) & ((unsigned)xx < 256u);
        v[t] = in ? (short)f2bu(xb[yy * 256 + xx]) : (short)0;
    }
    *(short8*)(xp8 + (size_t)idx * 8) = v;
}

// ---------------------------------------------------------------------------
__global__ __launch_bounds__(256) void nca_step(
    const ushort_t* __restrict__ stIn,   // [B][H][W][16] bf16 (unused if first)
    ushort_t* __restrict__ stOut,        // [B][H][W][16] bf16 (unused if last)
    const ushort_t* __restrict__ xp8g,   // [B][XPP][XPP][8] bf16
    const ushort_t* __restrict__ wh1p,
    const ushort_t* __restrict__ wu2f,
    const ushort_t* __restrict__ wtxf,
    const ushort_t* __restrict__ wtn,
    const float* __restrict__ scal,      // [64] beff | wxh8 | tb | wtx8
    const float* __restrict__ bu2G,
    const float* __restrict__ wrd,       // w_read [16]
    const float* __restrict__ brd,       // b_read [1]
    float* __restrict__ outg,            // [B][H][W] fp32 (used if last)
    int first, int last)
{
    __shared__ ushort_t comb[400 * PIT]; // 20x20 halo-2; LDS = 32000 B

    const int tid  = threadIdx.x;
    const int w    = tid >> 6, lane = tid & 63;
    const int m    = lane & 15, q = lane >> 4;
    const int och  = q * 4;              // base out-channel of this lane's D rows
    const int gx0  = blockIdx.x * 16, gy0 = blockIdx.y * 16;
    const size_t pb = (size_t)blockIdx.z * 65536;
    const size_t xpb = (size_t)blockIdx.z * (XPP * XPP);
    const short8 z8 = {0, 0, 0, 0, 0, 0, 0, 0};
    const float4v z4 = {0.f, 0.f, 0.f, 0.f};

    // all staged rows / h1 pixels / delta pixels in-image for this block?
    const bool interior = (blockIdx.x >= 1) & (blockIdx.x <= 14)
                        & (blockIdx.y >= 1) & (blockIdx.y <= 14);

    // per-wave weight fragments (used as MFMA *A* operands)
    short8 wh1r[5], wtnr[9];
#pragma unroll
    for (int i = 0; i < 5; ++i) wh1r[i] = *(const short8*)(wh1p + (i * 64 + lane) * 8);
#pragma unroll
    for (int t = 0; t < 9; ++t) wtnr[t] = *(const short8*)(wtn + (t * 64 + lane) * 8);
    const short8 wu2r = *(const short8*)(wu2f + lane * 8);
    const short8 wtxr = *(const short8*)(wtxf + lane * 8);

    // per-lane channel-quad biases (channels och..och+3)
    float4v beff4, bu24, wr4, tb4, wtx84;
#pragma unroll
    for (int r = 0; r < 4; ++r) {
        beff4[r] = scal[och + r];
        tb4[r]   = scal[32 + och + r];
        wtx84[r] = scal[48 + och + r];
        bu24[r]  = bu2G[och + r];
        wr4[r]   = wrd[och + r];
    }
    const float br = brd[0];

    // per-lane paired-tap B-read offsets (tap = 2*ii + (q>>1))
    const int sel = q >> 1;
    int offp[4];
#pragma unroll
    for (int ii = 0; ii < 4; ++ii) {
        int tA = 2 * ii, tB = 2 * ii + 1;
        int oA = ((tA / 3) * 20 + (tA % 3)) * PIT;
        int oB = ((tB / 3) * 20 + (tB % 3)) * PIT;
        offp[ii] = sel ? oB : oA;
    }
    const int chOff = 16 + (q & 1) * 8;
    const int t8off = (2 * 20 + 2) * PIT;
    // 5th-MFMA B offsets: q=0/1 -> state@tap8 (k0..15); q=2 -> x taps0..7
    // (k16..23); q=3 -> chunk4 of row (py+2,px+2): j=0 = x@tap8 (k24).
    const int off5  = (q == 0) ? (t8off + 16) : (q == 1) ? (t8off + 24)
                    : (q == 2) ? 32 : (t8off + 32);

    // ---- stage A: stage state ch16..31 + xpatch8 ch32..39 (coalesced) ------
    if (interior & (first == 0)) {
        for (int p = tid; p < 400; p += 256) {
            int ry = p / 20, rx = p - ry * 20;
            ushort_t* row = comb + p * PIT;
            const ushort_t* sp = stIn
                + (pb + (size_t)(gy0 + ry - 2) * 256 + (gx0 + rx - 2)) * 16;
            *(short8*)(row + 16) = *(const short8*)(sp);
            *(short8*)(row + 24) = *(const short8*)(sp + 8);
            *(short8*)(row + 32) = *(const short8*)(
                xp8g + (xpb + (size_t)(gy0 + ry) * XPP + (gx0 + rx)) * 8);
        }
    } else {
        for (int p = tid; p < 400; p += 256) {
            int ry = p / 20, rx = p - ry * 20;
            int gy = gy0 + ry - 2, gx = gx0 + rx - 2;
            ushort_t* row = comb + p * PIT;
            bool in = ((unsigned)gy < 256u) & ((unsigned)gx < 256u);
            if (in && !first) {
                const ushort_t* sp = stIn + (pb + gy * 256 + gx) * 16;
                *(short8*)(row + 16) = *(const short8*)(sp);
                *(short8*)(row + 24) = *(const short8*)(sp + 8);
            } else {
                *(short8*)(row + 16) = z8; *(short8*)(row + 24) = z8;
            }
            *(short8*)(row + 32) = *(const short8*)(
                xp8g + (xpb + (size_t)(gy0 + ry) * XPP + (gx0 + rx)) * 8);
        }
    }
    __syncthreads();

    // ---- stage B: 5-MFMA h1 conv (D[ch][pix]) -> up2 -> inline delta -------
    {
        int raw = w * 16 + m;                    // pixel index for i=0
        int py = raw / 18, px = raw - (raw / 18) * 18;
        for (int i = 0; i < 6; ++i) {
            int g = w + 4 * i; if (g >= 21) break;
            bool vld = raw < 324;
            int pyc = vld ? py : 17, pxc = vld ? px : 17;
            const ushort_t* abase = comb + (pyc * 20 + pxc) * PIT;
            float4v acc = z4;
            __builtin_amdgcn_s_setprio(1);
#pragma unroll
            for (int ii = 0; ii < 4; ++ii) {
                short8 b = *(const short8*)(abase + offp[ii] + chOff);
                acc = __builtin_amdgcn_mfma_f32_16x16x32_bf16(wh1r[ii], b, acc, 0, 0, 0);
            }
            {   // 5th: [state@tap8 || x@taps0..7 || x@tap8 || 0]
                short8 b = *(const short8*)(abase + off5);
                acc = __builtin_amdgcn_mfma_f32_16x16x32_bf16(wh1r[4], b, acc, 0, 0, 0);
            }
            __builtin_amdgcn_s_setprio(0);
            // epilogue: this lane owns pixel (pyc,pxc), channels och..och+3
            uint2 hv;
            {
                float h0 = fmaxf(acc[0] + beff4[0], 0.f);
                float h1 = fmaxf(acc[1] + beff4[1], 0.f);
                float h2 = fmaxf(acc[2] + beff4[2], 0.f);
                float h3 = fmaxf(acc[3] + beff4[3], 0.f);
                hv.x = pack2(h0, h1); hv.y = pack2(h2, h3);
            }
            // ZERO-SHUFFLE up2: lane (m,q) supplies B k-slots 8q..8q+7; wu2f
            // places channel 4q+jj at k-slot 8q+jj (jj<4) and 0 at jj>=4, so
            // this lane's own hv IS its B-fragment. Each channel is summed
            // exactly once (from the lane that computed it). No bpermute.
            union { unsigned u4[4]; short8 s8; } bb;
            bb.u4[0] = hv.x; bb.u4[1] = hv.y; bb.u4[2] = 0u; bb.u4[3] = 0u;
            float4v d = __builtin_amdgcn_mfma_f32_16x16x32_bf16(wu2r, bb.s8, z4, 0, 0, 0);
            // delta: pixel (pyc,pxc), channels och..och+3 -> one b64 write
            uint2 dv;
            dv.x = pack2(d[0] + bu24[0], d[1] + bu24[1]);
            dv.y = pack2(d[2] + bu24[2], d[3] + bu24[3]);
            if (!interior) {
                int gy = gy0 - 1 + pyc, gx = gx0 - 1 + pxc;
                bool im = ((unsigned)gy < 256u) & ((unsigned)gx < 256u);
                if (!im) { dv.x = 0u; dv.y = 0u; }   // ref zero-pads outside
            }
            if (vld)
                *(uint2*)(comb + ((pyc + 1) * 20 + (pxc + 1)) * PIT + och) = dv;
            // increment pixel index by 64: +3 rows +10 cols (mod 18)
            raw += 64; px += 10; py += 3;
            if (px >= 18) { px -= 18; py += 1; }
        }
    }
    __syncthreads();

    // ---- stage C: tau conv (D[ch][pix], K=32 [delta||state]) + x via MFMA --
    // Tap-row register cache: Ta = row g+1, Tb = row g+2 (dx = 0..2, chunk q);
    // per iteration load only the fresh row g+3, then rotate.
    {
        const int w4 = w * 4;
#define LDROW(r, dx) (*(const short8*)(comb + (((r) * 20) + (m + 1 + (dx))) * PIT + q * 8))
        short8 Ta0 = LDROW(w4 + 1, 0), Ta1 = LDROW(w4 + 1, 1), Ta2 = LDROW(w4 + 1, 2);
        short8 Tb0 = LDROW(w4 + 2, 0), Tb1 = LDROW(w4 + 2, 1), Tb2 = LDROW(w4 + 2, 2);
#pragma unroll
        for (int i = 0; i < 4; ++i) {
            int g = w4 + i;                      // core row; pixel col = m
            short8 Tc0 = LDROW(g + 3, 0), Tc1 = LDROW(g + 3, 1), Tc2 = LDROW(g + 3, 2);
            // xp taps 0..7 for the 10th MFMA (window base = core-(1,1))
            short8 bx = *(const short8*)(comb + ((g + 1) * 20 + (m + 1)) * PIT + 32);
            float4v acc = z4;
            __builtin_amdgcn_s_setprio(1);
            acc = __builtin_amdgcn_mfma_f32_16x16x32_bf16(wtnr[0], Ta0, acc, 0, 0, 0);
            acc = __builtin_amdgcn_mfma_f32_16x16x32_bf16(wtnr[1], Ta1, acc, 0, 0, 0);
            acc = __builtin_amdgcn_mfma_f32_16x16x32_bf16(wtnr[2], Ta2, acc, 0, 0, 0);
            acc = __builtin_amdgcn_mfma_f32_16x16x32_bf16(wtnr[3], Tb0, acc, 0, 0, 0);
            acc = __builtin_amdgcn_mfma_f32_16x16x32_bf16(wtnr[4], Tb1, acc, 0, 0, 0);
            acc = __builtin_amdgcn_mfma_f32_16x16x32_bf16(wtnr[5], Tb2, acc, 0, 0, 0);
            acc = __builtin_amdgcn_mfma_f32_16x16x32_bf16(wtnr[6], Tc0, acc, 0, 0, 0);
            acc = __builtin_amdgcn_mfma_f32_16x16x32_bf16(wtnr[7], Tc1, acc, 0, 0, 0);
            acc = __builtin_amdgcn_mfma_f32_16x16x32_bf16(wtnr[8], Tc2, acc, 0, 0, 0);
            acc = __builtin_amdgcn_mfma_f32_16x16x32_bf16(wtxr,   bx,  acc, 0, 0, 0);
            __builtin_amdgcn_s_setprio(0);
            int gy = gy0 + g;
            const size_t pix = pb + gy * 256 + gx0 + m;
            const ushort_t* cpx = comb + ((g + 2) * 20 + (m + 2)) * PIT;
            // tap 8 = x[core+(1,1)] = tap0 (ch32) of window based at (g+3,m+3)
            float x8c = bu2f(comb[((g + 3) * 20 + (m + 3)) * PIT + 32]);
            uint2 su = *(const uint2*)(cpx + 16 + och);        // state och..+3
            uint2 du = *(const uint2*)(cpx + och);             // delta
            float sold[4] = { lo2f(su.x), hi2f(su.x), lo2f(su.y), hi2f(su.y) };
            float dvv[4]  = { lo2f(du.x), hi2f(du.x), lo2f(du.y), hi2f(du.y) };
            float sn[4];
#pragma unroll
            for (int r = 0; r < 4; ++r) {
                float tl  = acc[r] + tb4[r] + x8c * wtx84[r];
                float e   = __expf(-tl);
                float bta = __builtin_amdgcn_rcpf(1.f + e);
                bta = __builtin_amdgcn_fmed3f(bta, 0.01f, 0.99f);
                sn[r] = dvv[r] + bta * (sold[r] - dvv[r]);
            }
            if (!last) {
                uint2 o;
                o.x = pack2(sn[0], sn[1]); o.y = pack2(sn[2], sn[3]);
                *(uint2*)(stOut + pix * 16 + och) = o;         // b64 store
            } else {
                // fused readout: channels spread over q -> butterfly on q bits
                float v = sn[0] * wr4[0] + sn[1] * wr4[1]
                        + sn[2] * wr4[2] + sn[3] * wr4[3];
                v += __shfl_xor(v, 16);
                v += __shfl_xor(v, 32);
                if (q == 0) {
                    float eo = __expf(-(v + br));
                    outg[pix] = __builtin_amdgcn_rcpf(1.f + eo);
                }
            }
            // rotate the row cache
            Ta0 = Tb0; Ta1 = Tb1; Ta2 = Tb2;
            Tb0 = Tc0; Tb1 = Tc1; Tb2 = Tc2;
        }
#undef LDROW
    }
}

// ---------------------------------------------------------------------------
extern "C" void kernel_launch(void* const* d_in, const int* in_sizes, int n_in,
                              void* d_out, int out_size, void* d_ws, size_t ws_size,
                              hipStream_t stream)
{
    const float* x          = (const float*)d_in[0];
    const float* w_perceive = (const float*)d_in[1];
    const float* b_perceive = (const float*)d_in[2];
    const float* w_up1      = (const float*)d_in[3];
    const float* b_up1      = (const float*)d_in[4];
    const float* w_up2      = (const float*)d_in[5];
    const float* b_up2      = (const float*)d_in[6];
    const float* w_tau      = (const float*)d_in[7];
    const float* b_tau_conv = (const float*)d_in[8];
    const float* b_tau      = (const float*)d_in[9];
    const float* w_read     = (const float*)d_in[10];
    const float* b_read     = (const float*)d_in[11];
    // d_in[12] = n_steps = 10 (host-known; hard-coded for graph capture)
    float* out = (float*)d_out;

    const size_t stateElems = (size_t)B_ * H_ * W_ * 16;     // 33,554,432 bf16
    const size_t xp8Elems   = (size_t)B_ * XPP * XPP * 8;    // 17,305,600 bf16

    // ws layout (~170 MB; tx tensor deleted)
    ushort_t* stA  = (ushort_t*)d_ws;
    ushort_t* stB  = stA + stateElems;
    ushort_t* xp8g = stB + stateElems;         // 34.6 MB
    ushort_t* wh1p = xp8g + xp8Elems;          // 2560
    ushort_t* wu2f = wh1p + 2560;              // 512
    ushort_t* wtxf = wu2f + 512;               // 512
    ushort_t* wtn  = wtxf + 512;               // 4608
    float*    scal = (float*)(wtn + 4608);     // 64 floats

    const size_t needBytes = (2 * stateElems + xp8Elems
                              + 2560 + 512 + 512 + 4608) * sizeof(ushort_t)
                           + 64 * sizeof(float);
    if (ws_size < needBytes) return;

    prep<<<dim3(1), dim3(256), 0, stream>>>(
        w_perceive, w_up1, b_up1, b_perceive, w_up2, w_tau,
        b_tau_conv, b_tau, wh1p, wu2f, wtxf, wtn, scal);
    precompute_xp8<<<dim3((B_ * XPP * XPP + 255) / 256), dim3(256), 0, stream>>>(
        x, xp8g);

    ushort_t* cur = stA;
    ushort_t* nxt = stB;
    for (int s = 0; s < 10; ++s) {
        nca_step<<<dim3(16, 16, 32), dim3(256), 0, stream>>>(
            cur, nxt, xp8g, wh1p, wu2f, wtxf, wtn, scal, b_up2,
            w_read, b_read, out, (s == 0) ? 1 : 0, (s == 9) ? 1 : 0);
        ushort_t* t = cur; cur = nxt; nxt = t;
    }
}

// Round 11
// 698.044 us; speedup vs baseline: 1.1647x; 1.0141x over previous
//
#include <hip/hip_runtime.h>
#include <hip/hip_bf16.h>
#include <math.h>

// LiquidNCA via bf16 MFMA, v3.15 = v3.14 (707.9 us best) + ONE isolated
// change: pack2 RHU bit-twiddle (5 VALU ops) -> __float22bfloat162_rn
// (1x v_cvt_pk_bf16_f32). ~32 packs/wave x 4 saved ops ~= 128 VALU ops/wave
// (~7% of the ~1700 measured VALU instrs/wave; VALU is the max pipe at 66%).
// RNE vs RHU differs only on exact ties (2^-16 probability/value); R5's
// bundled test already demonstrated absmax stays 0.00390625 with RNE.
// This was never tested in isolation -- R5 bundled it with the XCD swizzle
// (which regressed for L2-locality reasons) and R6 reverted both.
// v3.14 carried: fmed3 beta clamp; ZERO-SHUFFLE up2 (k-slot-remapped wu2f:
// in mfma(A,B) a k-permutation applied to both operands is identity, so lane
// (m,q)'s own hv is its B-fragment -- no bpermute), stage-C tap-row register
// cache, stage-B tap-8 folded into 5th MFMA at K=24, interior-block fast
// path, incremental py/px, setprio around conv MFMA clusters, tau x via 10th
// stage-C MFMA, no tx tensor (163 MB working set fits L3), LDS = 32000 B.
// Failed-and-reverted (do not retry): 2-step fusion (R6, halo recompute tax),
// stage-C global prefetch (R9, VMEM live-range + uncoalesced 2B gathers),
// XCD swizzle (R5, L2 locality loss at this access pattern).
// Core concept (R14-verified): mfma(weights, pixels, acc) -> D[channel][pixel]
// (A/B lane layouts are identical), so each lane owns 1 pixel x 4 consecutive
// channels and every epilogue access is one aligned b64.

#define B_   32
#define H_   256
#define W_   256
#define PIT  40                // comb pitch in ushorts (80 B, 16B-aligned)
#define XPP  260               // xp8pad padded dim (base gy in [-2, 257])

typedef unsigned short ushort_t;
typedef __attribute__((ext_vector_type(8))) short short8;
typedef __attribute__((ext_vector_type(4))) float float4v;

__device__ __forceinline__ unsigned fbits(float f) {
    union { float f; unsigned u; } v; v.f = f; return v.u;
}
__device__ __forceinline__ ushort_t f2bu(float f) {        // finite-only, RHU
    return (ushort_t)((fbits(f) + 0x8000u) >> 16);
}
__device__ __forceinline__ unsigned pack2(float lo, float hi) {  // RNE, 1 instr
    union { __hip_bfloat162 h; unsigned u; } v;
    v.h = __float22bfloat162_rn(make_float2(lo, hi));
    return v.u;
}
__device__ __forceinline__ float bu2f(ushort_t u) {
    union { unsigned i; float f; } v; v.i = ((unsigned)u) << 16; return v.f;
}
__device__ __forceinline__ float lo2f(unsigned u) {
    union { unsigned i; float f; } v; v.i = u << 16; return v.f;
}
__device__ __forceinline__ float hi2f(unsigned u) {
    union { unsigned i; float f; } v; v.i = u & 0xFFFF0000u; return v.f;
}

// ---------------------------------------------------------------------------
// prep: UNCHANGED from v3.12/v3.14.
__global__ void prep(
    const float* __restrict__ wp,   // [32][17][9]
    const float* __restrict__ wu1,  // [16][32]
    const float* __restrict__ bu1,  // [16]
    const float* __restrict__ bp,   // [32]
    const float* __restrict__ wu2,  // [16][16]
    const float* __restrict__ wt,   // [16][33][9]
    const float* __restrict__ btc,  // [16]
    const float* __restrict__ bt,   // [16]
    ushort_t* __restrict__ wh1p,    // [5][64][8]  4 pairs + (tap8||x0..8)
    ushort_t* __restrict__ wu2f,    // [64][8]
    ushort_t* __restrict__ wtxf,    // [64][8]  tau x-taps, K: 0..7 used
    ushort_t* __restrict__ wtn,     // [9][64][8]
    float* __restrict__ scal)       // [64] beff | wxh8 | tb | wtx8
{
    __shared__ float Weff[16 * 153];   // [n][c(0..16)][t]
    const int tid = threadIdx.x;

    for (int i = tid; i < 16 * 153; i += 256) {
        int j = i / 153, rem = i % 153, c = rem / 9, t = rem % 9;
        float s = 0.f;
        for (int o = 0; o < 32; ++o)
            s += wu1[j * 32 + o] * wp[o * 153 + c * 9 + t];
        Weff[i] = s;
    }
    if (tid < 16) {
        float s = bu1[tid];
        for (int o = 0; o < 32; ++o) s += wu1[tid * 32 + o] * bp[o];
        scal[tid] = s;                          // beff
    }
    if (tid < 16) scal[32 + tid] = btc[tid] + bt[tid];   // tau bias
    if (tid < 16) scal[48 + tid] = wt[tid * 297 + 8];    // tau tap-8 x weight
    __syncthreads();

    if (tid < 16) scal[16 + tid] = Weff[tid * 153 + 8];   // wxh8 (c=0, tap8)

    // pairs ii=0..3: K = [state@tap2ii (k0..15) || state@tap2ii+1 (k16..31)]
    for (int i = tid; i < 4 * 64 * 8; i += 256) {
        int ii = i >> 9, lane = (i >> 3) & 63, j = i & 7;
        int n = lane & 15, kk = ((lane >> 4) << 3) + j;
        int tap = 2 * ii + (kk >> 4), ch = kk & 15;
        wh1p[i] = f2bu(Weff[n * 153 + (ch + 1) * 9 + tap]);
    }
    // 5th: k<16 -> state@tap8; k=16..23 -> x@tap(k-16); k==24 -> x@tap8; else 0
    for (int i = tid; i < 512; i += 256) {
        int lane = i >> 3, j = i & 7;
        int n = lane & 15, k = ((lane >> 4) << 3) + j;
        float v = 0.f;
        if (k < 16)       v = Weff[n * 153 + (k + 1) * 9 + 8];
        else if (k < 24)  v = Weff[n * 153 + (k - 16)];      // c=0, tap k-16
        else if (k == 24) v = Weff[n * 153 + 8];             // c=0, tap 8
        wh1p[2048 + i] = f2bu(v);
    }
    // wu2f (zero-shuffle remap): k = 8a+b -> (b<4) ? wu2[n][4a+b] : 0
    for (int i = tid; i < 512; i += 256) {
        int lane = i >> 3, j = i & 7;
        int n = lane & 15, k = ((lane >> 4) << 3) + j;
        int a = k >> 3, b = k & 7;
        wu2f[i] = (b < 4) ? f2bu(wu2[n * 16 + 4 * a + b]) : (ushort_t)0;
    }
    // wtxf: tau x-tap weights wt[n][0][t], K-slot t = tap (0..7), else 0
    for (int i = tid; i < 512; i += 256) {
        int lane = i >> 3, j = i & 7;
        int n = lane & 15, k = ((lane >> 4) << 3) + j;
        wtxf[i] = (k < 8) ? f2bu(wt[n * 297 + k]) : (ushort_t)0;
    }
    // wtn: A = [delta(16) || state(16)] weights for tau
    for (int i = tid; i < 9 * 64 * 8; i += 256) {
        int t = i / 512, lane = (i / 8) % 64, j = i % 8;
        int n = lane & 15, k = ((lane >> 4) << 3) + j;
        int c = (k < 16) ? (17 + k) : (k - 15);
        wtn[i] = f2bu(wt[n * 297 + c * 9 + t]);
    }
}

// ---------------------------------------------------------------------------
// xp8pad[b][by][bx][8] = bf16 x at taps 0..7 of the 3x3 window based at
// global (by-2, bx-2); out-of-image taps are zero. tap0 = own x.
__global__ __launch_bounds__(256) void precompute_xp8(
    const float* __restrict__ x,     // [B][H][W] fp32
    ushort_t* __restrict__ xp8)      // [B][XPP][XPP][8] bf16
{
    int idx = blockIdx.x * 256 + threadIdx.x;
    if (idx >= B_ * XPP * XPP) return;
    int b  = idx / (XPP * XPP), rem = idx - b * (XPP * XPP);
    int by = rem / XPP, bx = rem - by * XPP;
    int gy = by - 2, gx = bx - 2;                 // window base in image coords
    const float* xb = x + (size_t)b * 65536;
    short8 v;
#pragma unroll
    for (int t = 0; t < 8; ++t) {
        int yy = gy + t / 3, xx = gx + t % 3;
        bool in = ((unsigned)yy < 256u) & ((unsigned)xx < 256u);
        v[t] = in ? (short)f2bu(xb[yy * 256 + xx]) : (short)0;
    }
    *(short8*)(xp8 + (size_t)idx * 8) = v;
}

// ---------------------------------------------------------------------------
__global__ __launch_bounds__(256) void nca_step(
    const ushort_t* __restrict__ stIn,   // [B][H][W][16] bf16 (unused if first)
    ushort_t* __restrict__ stOut,        // [B][H][W][16] bf16 (unused if last)
    const ushort_t* __restrict__ xp8g,   // [B][XPP][XPP][8] bf16
    const ushort_t* __restrict__ wh1p,
    const ushort_t* __restrict__ wu2f,
    const ushort_t* __restrict__ wtxf,
    const ushort_t* __restrict__ wtn,
    const float* __restrict__ scal,      // [64] beff | wxh8 | tb | wtx8
    const float* __restrict__ bu2G,
    const float* __restrict__ wrd,       // w_read [16]
    const float* __restrict__ brd,       // b_read [1]
    float* __restrict__ outg,            // [B][H][W] fp32 (used if last)
    int first, int last)
{
    __shared__ ushort_t comb[400 * PIT]; // 20x20 halo-2; LDS = 32000 B

    const int tid  = threadIdx.x;
    const int w    = tid >> 6, lane = tid & 63;
    const int m    = lane & 15, q = lane >> 4;
    const int och  = q * 4;              // base out-channel of this lane's D rows
    const int gx0  = blockIdx.x * 16, gy0 = blockIdx.y * 16;
    const size_t pb = (size_t)blockIdx.z * 65536;
    const size_t xpb = (size_t)blockIdx.z * (XPP * XPP);
    const short8 z8 = {0, 0, 0, 0, 0, 0, 0, 0};
    const float4v z4 = {0.f, 0.f, 0.f, 0.f};

    // all staged rows / h1 pixels / delta pixels in-image for this block?
    const bool interior = (blockIdx.x >= 1) & (blockIdx.x <= 14)
                        & (blockIdx.y >= 1) & (blockIdx.y <= 14);

    // per-wave weight fragments (used as MFMA *A* operands)
    short8 wh1r[5], wtnr[9];
#pragma unroll
    for (int i = 0; i < 5; ++i) wh1r[i] = *(const short8*)(wh1p + (i * 64 + lane) * 8);
#pragma unroll
    for (int t = 0; t < 9; ++t) wtnr[t] = *(const short8*)(wtn + (t * 64 + lane) * 8);
    const short8 wu2r = *(const short8*)(wu2f + lane * 8);
    const short8 wtxr = *(const short8*)(wtxf + lane * 8);

    // per-lane channel-quad biases (channels och..och+3)
    float4v beff4, bu24, wr4, tb4, wtx84;
#pragma unroll
    for (int r = 0; r < 4; ++r) {
        beff4[r] = scal[och + r];
        tb4[r]   = scal[32 + och + r];
        wtx84[r] = scal[48 + och + r];
        bu24[r]  = bu2G[och + r];
        wr4[r]   = wrd[och + r];
    }
    const float br = brd[0];

    // per-lane paired-tap B-read offsets (tap = 2*ii + (q>>1))
    const int sel = q >> 1;
    int offp[4];
#pragma unroll
    for (int ii = 0; ii < 4; ++ii) {
        int tA = 2 * ii, tB = 2 * ii + 1;
        int oA = ((tA / 3) * 20 + (tA % 3)) * PIT;
        int oB = ((tB / 3) * 20 + (tB % 3)) * PIT;
        offp[ii] = sel ? oB : oA;
    }
    const int chOff = 16 + (q & 1) * 8;
    const int t8off = (2 * 20 + 2) * PIT;
    // 5th-MFMA B offsets: q=0/1 -> state@tap8 (k0..15); q=2 -> x taps0..7
    // (k16..23); q=3 -> chunk4 of row (py+2,px+2): j=0 = x@tap8 (k24).
    const int off5  = (q == 0) ? (t8off + 16) : (q == 1) ? (t8off + 24)
                    : (q == 2) ? 32 : (t8off + 32);

    // ---- stage A: stage state ch16..31 + xpatch8 ch32..39 (coalesced) ------
    if (interior & (first == 0)) {
        for (int p = tid; p < 400; p += 256) {
            int ry = p / 20, rx = p - ry * 20;
            ushort_t* row = comb + p * PIT;
            const ushort_t* sp = stIn
                + (pb + (size_t)(gy0 + ry - 2) * 256 + (gx0 + rx - 2)) * 16;
            *(short8*)(row + 16) = *(const short8*)(sp);
            *(short8*)(row + 24) = *(const short8*)(sp + 8);
            *(short8*)(row + 32) = *(const short8*)(
                xp8g + (xpb + (size_t)(gy0 + ry) * XPP + (gx0 + rx)) * 8);
        }
    } else {
        for (int p = tid; p < 400; p += 256) {
            int ry = p / 20, rx = p - ry * 20;
            int gy = gy0 + ry - 2, gx = gx0 + rx - 2;
            ushort_t* row = comb + p * PIT;
            bool in = ((unsigned)gy < 256u) & ((unsigned)gx < 256u);
            if (in && !first) {
                const ushort_t* sp = stIn + (pb + gy * 256 + gx) * 16;
                *(short8*)(row + 16) = *(const short8*)(sp);
                *(short8*)(row + 24) = *(const short8*)(sp + 8);
            } else {
                *(short8*)(row + 16) = z8; *(short8*)(row + 24) = z8;
            }
            *(short8*)(row + 32) = *(const short8*)(
                xp8g + (xpb + (size_t)(gy0 + ry) * XPP + (gx0 + rx)) * 8);
        }
    }
    __syncthreads();

    // ---- stage B: 5-MFMA h1 conv (D[ch][pix]) -> up2 -> inline delta -------
    {
        int raw = w * 16 + m;                    // pixel index for i=0
        int py = raw / 18, px = raw - (raw / 18) * 18;
        for (int i = 0; i < 6; ++i) {
            int g = w + 4 * i; if (g >= 21) break;
            bool vld = raw < 324;
            int pyc = vld ? py : 17, pxc = vld ? px : 17;
            const ushort_t* abase = comb + (pyc * 20 + pxc) * PIT;
            float4v acc = z4;
            __builtin_amdgcn_s_setprio(1);
#pragma unroll
            for (int ii = 0; ii < 4; ++ii) {
                short8 b = *(const short8*)(abase + offp[ii] + chOff);
                acc = __builtin_amdgcn_mfma_f32_16x16x32_bf16(wh1r[ii], b, acc, 0, 0, 0);
            }
            {   // 5th: [state@tap8 || x@taps0..7 || x@tap8 || 0]
                short8 b = *(const short8*)(abase + off5);
                acc = __builtin_amdgcn_mfma_f32_16x16x32_bf16(wh1r[4], b, acc, 0, 0, 0);
            }
            __builtin_amdgcn_s_setprio(0);
            // epilogue: this lane owns pixel (pyc,pxc), channels och..och+3
            uint2 hv;
            hv.x = pack2(fmaxf(acc[0] + beff4[0], 0.f),
                         fmaxf(acc[1] + beff4[1], 0.f));
            hv.y = pack2(fmaxf(acc[2] + beff4[2], 0.f),
                         fmaxf(acc[3] + beff4[3], 0.f));
            // ZERO-SHUFFLE up2: lane (m,q) supplies B k-slots 8q..8q+7; wu2f
            // places channel 4q+jj at k-slot 8q+jj (jj<4) and 0 at jj>=4, so
            // this lane's own hv IS its B-fragment. Each channel is summed
            // exactly once (from the lane that computed it). No bpermute.
            union { unsigned u4[4]; short8 s8; } bb;
            bb.u4[0] = hv.x; bb.u4[1] = hv.y; bb.u4[2] = 0u; bb.u4[3] = 0u;
            float4v d = __builtin_amdgcn_mfma_f32_16x16x32_bf16(wu2r, bb.s8, z4, 0, 0, 0);
            // delta: pixel (pyc,pxc), channels och..och+3 -> one b64 write
            uint2 dv;
            dv.x = pack2(d[0] + bu24[0], d[1] + bu24[1]);
            dv.y = pack2(d[2] + bu24[2], d[3] + bu24[3]);
            if (!interior) {
                int gy = gy0 - 1 + pyc, gx = gx0 - 1 + pxc;
                bool im = ((unsigned)gy < 256u) & ((unsigned)gx < 256u);
                if (!im) { dv.x = 0u; dv.y = 0u; }   // ref zero-pads outside
            }
            if (vld)
                *(uint2*)(comb + ((pyc + 1) * 20 + (pxc + 1)) * PIT + och) = dv;
            // increment pixel index by 64: +3 rows +10 cols (mod 18)
            raw += 64; px += 10; py += 3;
            if (px >= 18) { px -= 18; py += 1; }
        }
    }
    __syncthreads();

    // ---- stage C: tau conv (D[ch][pix], K=32 [delta||state]) + x via MFMA --
    // Tap-row register cache: Ta = row g+1, Tb = row g+2 (dx = 0..2, chunk q);
    // per iteration load only the fresh row g+3, then rotate.
    {
        const int w4 = w * 4;
#define LDROW(r, dx) (*(const short8*)(comb + (((r) * 20) + (m + 1 + (dx))) * PIT + q * 8))
        short8 Ta0 = LDROW(w4 + 1, 0), Ta1 = LDROW(w4 + 1, 1), Ta2 = LDROW(w4 + 1, 2);
        short8 Tb0 = LDROW(w4 + 2, 0), Tb1 = LDROW(w4 + 2, 1), Tb2 = LDROW(w4 + 2, 2);
#pragma unroll
        for (int i = 0; i < 4; ++i) {
            int g = w4 + i;                      // core row; pixel col = m
            short8 Tc0 = LDROW(g + 3, 0), Tc1 = LDROW(g + 3, 1), Tc2 = LDROW(g + 3, 2);
            // xp taps 0..7 for the 10th MFMA (window base = core-(1,1))
            short8 bx = *(const short8*)(comb + ((g + 1) * 20 + (m + 1)) * PIT + 32);
            float4v acc = z4;
            __builtin_amdgcn_s_setprio(1);
            acc = __builtin_amdgcn_mfma_f32_16x16x32_bf16(wtnr[0], Ta0, acc, 0, 0, 0);
            acc = __builtin_amdgcn_mfma_f32_16x16x32_bf16(wtnr[1], Ta1, acc, 0, 0, 0);
            acc = __builtin_amdgcn_mfma_f32_16x16x32_bf16(wtnr[2], Ta2, acc, 0, 0, 0);
            acc = __builtin_amdgcn_mfma_f32_16x16x32_bf16(wtnr[3], Tb0, acc, 0, 0, 0);
            acc = __builtin_amdgcn_mfma_f32_16x16x32_bf16(wtnr[4], Tb1, acc, 0, 0, 0);
            acc = __builtin_amdgcn_mfma_f32_16x16x32_bf16(wtnr[5], Tb2, acc, 0, 0, 0);
            acc = __builtin_amdgcn_mfma_f32_16x16x32_bf16(wtnr[6], Tc0, acc, 0, 0, 0);
            acc = __builtin_amdgcn_mfma_f32_16x16x32_bf16(wtnr[7], Tc1, acc, 0, 0, 0);
            acc = __builtin_amdgcn_mfma_f32_16x16x32_bf16(wtnr[8], Tc2, acc, 0, 0, 0);
            acc = __builtin_amdgcn_mfma_f32_16x16x32_bf16(wtxr,   bx,  acc, 0, 0, 0);
            __builtin_amdgcn_s_setprio(0);
            int gy = gy0 + g;
            const size_t pix = pb + gy * 256 + gx0 + m;
            const ushort_t* cpx = comb + ((g + 2) * 20 + (m + 2)) * PIT;
            // tap 8 = x[core+(1,1)] = tap0 (ch32) of window based at (g+3,m+3)
            float x8c = bu2f(comb[((g + 3) * 20 + (m + 3)) * PIT + 32]);
            uint2 su = *(const uint2*)(cpx + 16 + och);        // state och..+3
            uint2 du = *(const uint2*)(cpx + och);             // delta
            float sold[4] = { lo2f(su.x), hi2f(su.x), lo2f(su.y), hi2f(su.y) };
            float dvv[4]  = { lo2f(du.x), hi2f(du.x), lo2f(du.y), hi2f(du.y) };
            float sn[4];
#pragma unroll
            for (int r = 0; r < 4; ++r) {
                float tl  = acc[r] + tb4[r] + x8c * wtx84[r];
                float e   = __expf(-tl);
                float bta = __builtin_amdgcn_rcpf(1.f + e);
                bta = __builtin_amdgcn_fmed3f(bta, 0.01f, 0.99f);
                sn[r] = dvv[r] + bta * (sold[r] - dvv[r]);
            }
            if (!last) {
                uint2 o;
                o.x = pack2(sn[0], sn[1]); o.y = pack2(sn[2], sn[3]);
                *(uint2*)(stOut + pix * 16 + och) = o;         // b64 store
            } else {
                // fused readout: channels spread over q -> butterfly on q bits
                float v = sn[0] * wr4[0] + sn[1] * wr4[1]
                        + sn[2] * wr4[2] + sn[3] * wr4[3];
                v += __shfl_xor(v, 16);
                v += __shfl_xor(v, 32);
                if (q == 0) {
                    float eo = __expf(-(v + br));
                    outg[pix] = __builtin_amdgcn_rcpf(1.f + eo);
                }
            }
            // rotate the row cache
            Ta0 = Tb0; Ta1 = Tb1; Ta2 = Tb2;
            Tb0 = Tc0; Tb1 = Tc1; Tb2 = Tc2;
        }
#undef LDROW
    }
}

// ---------------------------------------------------------------------------
extern "C" void kernel_launch(void* const* d_in, const int* in_sizes, int n_in,
                              void* d_out, int out_size, void* d_ws, size_t ws_size,
                              hipStream_t stream)
{
    const float* x          = (const float*)d_in[0];
    const float* w_perceive = (const float*)d_in[1];
    const float* b_perceive = (const float*)d_in[2];
    const float* w_up1      = (const float*)d_in[3];
    const float* b_up1      = (const float*)d_in[4];
    const float* w_up2      = (const float*)d_in[5];
    const float* b_up2      = (const float*)d_in[6];
    const float* w_tau      = (const float*)d_in[7];
    const float* b_tau_conv = (const float*)d_in[8];
    const float* b_tau      = (const float*)d_in[9];
    const float* w_read     = (const float*)d_in[10];
    const float* b_read     = (const float*)d_in[11];
    // d_in[12] = n_steps = 10 (host-known; hard-coded for graph capture)
    float* out = (float*)d_out;

    const size_t stateElems = (size_t)B_ * H_ * W_ * 16;     // 33,554,432 bf16
    const size_t xp8Elems   = (size_t)B_ * XPP * XPP * 8;    // 17,305,600 bf16

    // ws layout (~170 MB; tx tensor deleted)
    ushort_t* stA  = (ushort_t*)d_ws;
    ushort_t* stB  = stA + stateElems;
    ushort_t* xp8g = stB + stateElems;         // 34.6 MB
    ushort_t* wh1p = xp8g + xp8Elems;          // 2560
    ushort_t* wu2f = wh1p + 2560;              // 512
    ushort_t* wtxf = wu2f + 512;               // 512
    ushort_t* wtn  = wtxf + 512;               // 4608
    float*    scal = (float*)(wtn + 4608);     // 64 floats

    const size_t needBytes = (2 * stateElems + xp8Elems
                              + 2560 + 512 + 512 + 4608) * sizeof(ushort_t)
                           + 64 * sizeof(float);
    if (ws_size < needBytes) return;

    prep<<<dim3(1), dim3(256), 0, stream>>>(
        w_perceive, w_up1, b_up1, b_perceive, w_up2, w_tau,
        b_tau_conv, b_tau, wh1p, wu2f, wtxf, wtn, scal);
    precompute_xp8<<<dim3((B_ * XPP * XPP + 255) / 256), dim3(256), 0, stream>>>(
        x, xp8g);

    ushort_t* cur = stA;
    ushort_t* nxt = stB;
    for (int s = 0; s < 10; ++s) {
        nca_step<<<dim3(16, 16, 32), dim3(256), 0, stream>>>(
            cur, nxt, xp8g, wh1p, wu2f, wtxf, wtn, scal, b_up2,
            w_read, b_read, out, (s == 0) ? 1 : 0, (s == 9) ? 1 : 0);
        ushort_t* t = cur; cur = nxt; nxt = t;
    }
}

// Round 12
// 695.843 us; speedup vs baseline: 1.1684x; 1.0032x over previous
//
#include <hip/hip_runtime.h>
#include <hip/hip_bf16.h>
#include <math.h>

// LiquidNCA via bf16 MFMA, v3.16 = v3.15 (698 us best) + 16x32 TILE / 512
// THREADS (8 waves). Pure work-reduction, per-pixel math untouched:
//  - staging: 20x36=720 halo rows for a 16x32 core vs 2x400 for two 16x16
//    blocks (-10% staged bytes + address math);
//  - stage B: delta region 18x34=612 px -> 39 MFMA groups vs 2x21=42 (-7%),
//    and the per-wave critical path drops 6 -> 5 iterations (waves 0-6 do 5,
//    wave 7 does 4) -- the old 16x16 tile charged every block a 6-iter wave;
//  - stage C: 32 groups / 8 waves = 4 each, perfectly balanced (as before);
//  - LDS 57600 B -> 2 blocks/CU = 16 waves/CU >= the 12.3 measured, so
//    occupancy does not drop. Grid 8192 -> 4096 blocks.
// All v3.15 techniques carried verbatim: RNE cvt_pk pack, fmed3 clamp,
// ZERO-SHUFFLE up2 (k-slot-remapped wu2f), stage-C tap-row register cache,
// stage-B tap-8 folded into 5th MFMA at K=24, interior fast path,
// incremental py/px, setprio around MFMA clusters, tau x via 10th stage-C
// MFMA, no tx tensor (163 MB working set fits L3).
// Failed-and-reverted (do not retry): 2-step fusion (R6), stage-C global
// prefetch (R9), XCD swizzle (R5).
// Core concept (R14-verified): mfma(weights, pixels, acc) -> D[channel][pixel]
// (A/B lane layouts are identical), so each lane owns 1 pixel x 4 consecutive
// channels and every epilogue access is one aligned b64.

#define B_   32
#define H_   256
#define W_   256
#define PIT  40                // comb pitch in ushorts (80 B, 16B-aligned)
#define XPP  260               // xp8pad padded dim (base gy in [-2, 257])
#define TW   36                // comb width  (32 + 4 halo)
#define TH   20                // comb height (16 + 4 halo)

typedef unsigned short ushort_t;
typedef __attribute__((ext_vector_type(8))) short short8;
typedef __attribute__((ext_vector_type(4))) float float4v;

__device__ __forceinline__ unsigned fbits(float f) {
    union { float f; unsigned u; } v; v.f = f; return v.u;
}
__device__ __forceinline__ ushort_t f2bu(float f) {        // finite-only, RHU
    return (ushort_t)((fbits(f) + 0x8000u) >> 16);
}
__device__ __forceinline__ unsigned pack2(float lo, float hi) {  // RNE, 1 instr
    union { __hip_bfloat162 h; unsigned u; } v;
    v.h = __float22bfloat162_rn(make_float2(lo, hi));
    return v.u;
}
__device__ __forceinline__ float bu2f(ushort_t u) {
    union { unsigned i; float f; } v; v.i = ((unsigned)u) << 16; return v.f;
}
__device__ __forceinline__ float lo2f(unsigned u) {
    union { unsigned i; float f; } v; v.i = u << 16; return v.f;
}
__device__ __forceinline__ float hi2f(unsigned u) {
    union { unsigned i; float f; } v; v.i = u & 0xFFFF0000u; return v.f;
}

// ---------------------------------------------------------------------------
// prep: UNCHANGED from v3.12/v3.15.
__global__ void prep(
    const float* __restrict__ wp,   // [32][17][9]
    const float* __restrict__ wu1,  // [16][32]
    const float* __restrict__ bu1,  // [16]
    const float* __restrict__ bp,   // [32]
    const float* __restrict__ wu2,  // [16][16]
    const float* __restrict__ wt,   // [16][33][9]
    const float* __restrict__ btc,  // [16]
    const float* __restrict__ bt,   // [16]
    ushort_t* __restrict__ wh1p,    // [5][64][8]  4 pairs + (tap8||x0..8)
    ushort_t* __restrict__ wu2f,    // [64][8]
    ushort_t* __restrict__ wtxf,    // [64][8]  tau x-taps, K: 0..7 used
    ushort_t* __restrict__ wtn,     // [9][64][8]
    float* __restrict__ scal)       // [64] beff | wxh8 | tb | wtx8
{
    __shared__ float Weff[16 * 153];   // [n][c(0..16)][t]
    const int tid = threadIdx.x;

    for (int i = tid; i < 16 * 153; i += 256) {
        int j = i / 153, rem = i % 153, c = rem / 9, t = rem % 9;
        float s = 0.f;
        for (int o = 0; o < 32; ++o)
            s += wu1[j * 32 + o] * wp[o * 153 + c * 9 + t];
        Weff[i] = s;
    }
    if (tid < 16) {
        float s = bu1[tid];
        for (int o = 0; o < 32; ++o) s += wu1[tid * 32 + o] * bp[o];
        scal[tid] = s;                          // beff
    }
    if (tid < 16) scal[32 + tid] = btc[tid] + bt[tid];   // tau bias
    if (tid < 16) scal[48 + tid] = wt[tid * 297 + 8];    // tau tap-8 x weight
    __syncthreads();

    if (tid < 16) scal[16 + tid] = Weff[tid * 153 + 8];   // wxh8 (c=0, tap8)

    // pairs ii=0..3: K = [state@tap2ii (k0..15) || state@tap2ii+1 (k16..31)]
    for (int i = tid; i < 4 * 64 * 8; i += 256) {
        int ii = i >> 9, lane = (i >> 3) & 63, j = i & 7;
        int n = lane & 15, kk = ((lane >> 4) << 3) + j;
        int tap = 2 * ii + (kk >> 4), ch = kk & 15;
        wh1p[i] = f2bu(Weff[n * 153 + (ch + 1) * 9 + tap]);
    }
    // 5th: k<16 -> state@tap8; k=16..23 -> x@tap(k-16); k==24 -> x@tap8; else 0
    for (int i = tid; i < 512; i += 256) {
        int lane = i >> 3, j = i & 7;
        int n = lane & 15, k = ((lane >> 4) << 3) + j;
        float v = 0.f;
        if (k < 16)       v = Weff[n * 153 + (k + 1) * 9 + 8];
        else if (k < 24)  v = Weff[n * 153 + (k - 16)];      // c=0, tap k-16
        else if (k == 24) v = Weff[n * 153 + 8];             // c=0, tap 8
        wh1p[2048 + i] = f2bu(v);
    }
    // wu2f (zero-shuffle remap): k = 8a+b -> (b<4) ? wu2[n][4a+b] : 0
    for (int i = tid; i < 512; i += 256) {
        int lane = i >> 3, j = i & 7;
        int n = lane & 15, k = ((lane >> 4) << 3) + j;
        int a = k >> 3, b = k & 7;
        wu2f[i] = (b < 4) ? f2bu(wu2[n * 16 + 4 * a + b]) : (ushort_t)0;
    }
    // wtxf: tau x-tap weights wt[n][0][t], K-slot t = tap (0..7), else 0
    for (int i = tid; i < 512; i += 256) {
        int lane = i >> 3, j = i & 7;
        int n = lane & 15, k = ((lane >> 4) << 3) + j;
        wtxf[i] = (k < 8) ? f2bu(wt[n * 297 + k]) : (ushort_t)0;
    }
    // wtn: A = [delta(16) || state(16)] weights for tau
    for (int i = tid; i < 9 * 64 * 8; i += 256) {
        int t = i / 512, lane = (i / 8) % 64, j = i % 8;
        int n = lane & 15, k = ((lane >> 4) << 3) + j;
        int c = (k < 16) ? (17 + k) : (k - 15);
        wtn[i] = f2bu(wt[n * 297 + c * 9 + t]);
    }
}

// ---------------------------------------------------------------------------
// xp8pad[b][by][bx][8] = bf16 x at taps 0..7 of the 3x3 window based at
// global (by-2, bx-2); out-of-image taps are zero. tap0 = own x.
__global__ __launch_bounds__(256) void precompute_xp8(
    const float* __restrict__ x,     // [B][H][W] fp32
    ushort_t* __restrict__ xp8)      // [B][XPP][XPP][8] bf16
{
    int idx = blockIdx.x * 256 + threadIdx.x;
    if (idx >= B_ * XPP * XPP) return;
    int b  = idx / (XPP * XPP), rem = idx - b * (XPP * XPP);
    int by = rem / XPP, bx = rem - by * XPP;
    int gy = by - 2, gx = bx - 2;                 // window base in image coords
    const float* xb = x + (size_t)b * 65536;
    short8 v;
#pragma unroll
    for (int t = 0; t < 8; ++t) {
        int yy = gy + t / 3, xx = gx + t % 3;
        bool in = ((unsigned)yy < 256u) & ((unsigned)xx < 256u);
        v[t] = in ? (short)f2bu(xb[yy * 256 + xx]) : (short)0;
    }
    *(short8*)(xp8 + (size_t)idx * 8) = v;
}

// ---------------------------------------------------------------------------
__global__ __launch_bounds__(512) void nca_step(
    const ushort_t* __restrict__ stIn,   // [B][H][W][16] bf16 (unused if first)
    ushort_t* __restrict__ stOut,        // [B][H][W][16] bf16 (unused if last)
    const ushort_t* __restrict__ xp8g,   // [B][XPP][XPP][8] bf16
    const ushort_t* __restrict__ wh1p,
    const ushort_t* __restrict__ wu2f,
    const ushort_t* __restrict__ wtxf,
    const ushort_t* __restrict__ wtn,
    const float* __restrict__ scal,      // [64] beff | wxh8 | tb | wtx8
    const float* __restrict__ bu2G,
    const float* __restrict__ wrd,       // w_read [16]
    const float* __restrict__ brd,       // b_read [1]
    float* __restrict__ outg,            // [B][H][W] fp32 (used if last)
    int first, int last)
{
    __shared__ ushort_t comb[TH * TW * PIT]; // 20x36 halo-4; 57600 B -> 2 blk/CU

    const int tid  = threadIdx.x;
    const int w    = tid >> 6, lane = tid & 63;
    const int m    = lane & 15, q = lane >> 4;
    const int och  = q * 4;              // base out-channel of this lane's D rows
    const int gx0  = blockIdx.x * 32, gy0 = blockIdx.y * 16;
    const size_t pb = (size_t)blockIdx.z * 65536;
    const size_t xpb = (size_t)blockIdx.z * (XPP * XPP);
    const short8 z8 = {0, 0, 0, 0, 0, 0, 0, 0};
    const float4v z4 = {0.f, 0.f, 0.f, 0.f};

    // all staged rows / h1 pixels / delta pixels in-image for this block?
    const bool interior = (blockIdx.x >= 1) & (blockIdx.x <= 6)
                        & (blockIdx.y >= 1) & (blockIdx.y <= 14);

    // per-wave weight fragments (used as MFMA *A* operands)
    short8 wh1r[5], wtnr[9];
#pragma unroll
    for (int i = 0; i < 5; ++i) wh1r[i] = *(const short8*)(wh1p + (i * 64 + lane) * 8);
#pragma unroll
    for (int t = 0; t < 9; ++t) wtnr[t] = *(const short8*)(wtn + (t * 64 + lane) * 8);
    const short8 wu2r = *(const short8*)(wu2f + lane * 8);
    const short8 wtxr = *(const short8*)(wtxf + lane * 8);

    // per-lane channel-quad biases (channels och..och+3)
    float4v beff4, bu24, wr4, tb4, wtx84;
#pragma unroll
    for (int r = 0; r < 4; ++r) {
        beff4[r] = scal[och + r];
        tb4[r]   = scal[32 + och + r];
        wtx84[r] = scal[48 + och + r];
        bu24[r]  = bu2G[och + r];
        wr4[r]   = wrd[och + r];
    }
    const float br = brd[0];

    // per-lane paired-tap B-read offsets (tap = 2*ii + (q>>1)), grid width TW
    const int sel = q >> 1;
    int offp[4];
#pragma unroll
    for (int ii = 0; ii < 4; ++ii) {
        int tA = 2 * ii, tB = 2 * ii + 1;
        int oA = ((tA / 3) * TW + (tA % 3)) * PIT;
        int oB = ((tB / 3) * TW + (tB % 3)) * PIT;
        offp[ii] = sel ? oB : oA;
    }
    const int chOff = 16 + (q & 1) * 8;
    const int t8off = (2 * TW + 2) * PIT;
    // 5th-MFMA B offsets: q=0/1 -> state@tap8 (k0..15); q=2 -> x taps0..7
    // (k16..23); q=3 -> chunk4 of row (py+2,px+2): j=0 = x@tap8 (k24).
    const int off5  = (q == 0) ? (t8off + 16) : (q == 1) ? (t8off + 24)
                    : (q == 2) ? 32 : (t8off + 32);

    // ---- stage A: stage state ch16..31 + xpatch8 ch32..39 (coalesced) ------
    if (interior & (first == 0)) {
        for (int p = tid; p < TH * TW; p += 512) {
            int ry = p / TW, rx = p - ry * TW;
            ushort_t* row = comb + p * PIT;
            const ushort_t* sp = stIn
                + (pb + (size_t)(gy0 + ry - 2) * 256 + (gx0 + rx - 2)) * 16;
            *(short8*)(row + 16) = *(const short8*)(sp);
            *(short8*)(row + 24) = *(const short8*)(sp + 8);
            *(short8*)(row + 32) = *(const short8*)(
                xp8g + (xpb + (size_t)(gy0 + ry) * XPP + (gx0 + rx)) * 8);
        }
    } else {
        for (int p = tid; p < TH * TW; p += 512) {
            int ry = p / TW, rx = p - ry * TW;
            int gy = gy0 + ry - 2, gx = gx0 + rx - 2;
            ushort_t* row = comb + p * PIT;
            bool in = ((unsigned)gy < 256u) & ((unsigned)gx < 256u);
            if (in && !first) {
                const ushort_t* sp = stIn + (pb + gy * 256 + gx) * 16;
                *(short8*)(row + 16) = *(const short8*)(sp);
                *(short8*)(row + 24) = *(const short8*)(sp + 8);
            } else {
                *(short8*)(row + 16) = z8; *(short8*)(row + 24) = z8;
            }
            *(short8*)(row + 32) = *(const short8*)(
                xp8g + (xpb + (size_t)(gy0 + ry) * XPP + (gx0 + rx)) * 8);
        }
    }
    __syncthreads();

    // ---- stage B: 5-MFMA h1 conv (D[ch][pix]) -> up2 -> inline delta -------
    // delta region 18x34 = 612 pixels -> 39 groups of 16; wave w takes
    // groups w, w+8, ... (waves 0-6: 5 iters, wave 7: 4).
    {
        int raw = w * 16 + m;                    // pixel index for i=0
        int py = raw / 34, px = raw - (raw / 34) * 34;
        for (int i = 0; i < 5; ++i) {
            int g = w + 8 * i; if (g >= 39) break;
            bool vld = raw < 612;
            int pyc = vld ? py : 17, pxc = vld ? px : 33;
            const ushort_t* abase = comb + (pyc * TW + pxc) * PIT;
            float4v acc = z4;
            __builtin_amdgcn_s_setprio(1);
#pragma unroll
            for (int ii = 0; ii < 4; ++ii) {
                short8 b = *(const short8*)(abase + offp[ii] + chOff);
                acc = __builtin_amdgcn_mfma_f32_16x16x32_bf16(wh1r[ii], b, acc, 0, 0, 0);
            }
            {   // 5th: [state@tap8 || x@taps0..7 || x@tap8 || 0]
                short8 b = *(const short8*)(abase + off5);
                acc = __builtin_amdgcn_mfma_f32_16x16x32_bf16(wh1r[4], b, acc, 0, 0, 0);
            }
            __builtin_amdgcn_s_setprio(0);
            // epilogue: this lane owns pixel (pyc,pxc), channels och..och+3
            uint2 hv;
            hv.x = pack2(fmaxf(acc[0] + beff4[0], 0.f),
                         fmaxf(acc[1] + beff4[1], 0.f));
            hv.y = pack2(fmaxf(acc[2] + beff4[2], 0.f),
                         fmaxf(acc[3] + beff4[3], 0.f));
            // ZERO-SHUFFLE up2: lane (m,q) supplies B k-slots 8q..8q+7; wu2f
            // places channel 4q+jj at k-slot 8q+jj (jj<4) and 0 at jj>=4, so
            // this lane's own hv IS its B-fragment. No bpermute.
            union { unsigned u4[4]; short8 s8; } bb;
            bb.u4[0] = hv.x; bb.u4[1] = hv.y; bb.u4[2] = 0u; bb.u4[3] = 0u;
            float4v d = __builtin_amdgcn_mfma_f32_16x16x32_bf16(wu2r, bb.s8, z4, 0, 0, 0);
            // delta: pixel (pyc,pxc), channels och..och+3 -> one b64 write
            uint2 dv;
            dv.x = pack2(d[0] + bu24[0], d[1] + bu24[1]);
            dv.y = pack2(d[2] + bu24[2], d[3] + bu24[3]);
            if (!interior) {
                int gy = gy0 - 1 + pyc, gx = gx0 - 1 + pxc;
                bool im = ((unsigned)gy < 256u) & ((unsigned)gx < 256u);
                if (!im) { dv.x = 0u; dv.y = 0u; }   // ref zero-pads outside
            }
            if (vld)
                *(uint2*)(comb + ((pyc + 1) * TW + (pxc + 1)) * PIT + och) = dv;
            // increment pixel index by 128: +3 rows +26 cols (mod 34)
            raw += 128; px += 26; py += 3;
            if (px >= 34) { px -= 34; py += 1; }
        }
    }
    __syncthreads();

    // ---- stage C: tau conv (D[ch][pix], K=32 [delta||state]) + x via MFMA --
    // 32 groups (16 rows x 2 col-halves) / 8 waves = 4 each, balanced.
    // Wave w: col-half w&1 (cols m2 = (w&1)*16 + m), rows (w>>1)*4 + i.
    // Tap-row register cache: Ta = row g+1, Tb = row g+2 (dx = 0..2, chunk q).
    {
        const int m2 = ((w & 1) << 4) + m;
        const int g0 = (w >> 1) * 4;
#define LDROW(r, dx) (*(const short8*)(comb + (((r) * TW) + (m2 + 1 + (dx))) * PIT + q * 8))
        short8 Ta0 = LDROW(g0 + 1, 0), Ta1 = LDROW(g0 + 1, 1), Ta2 = LDROW(g0 + 1, 2);
        short8 Tb0 = LDROW(g0 + 2, 0), Tb1 = LDROW(g0 + 2, 1), Tb2 = LDROW(g0 + 2, 2);
#pragma unroll
        for (int i = 0; i < 4; ++i) {
            int g = g0 + i;                      // core row; pixel col = m2
            short8 Tc0 = LDROW(g + 3, 0), Tc1 = LDROW(g + 3, 1), Tc2 = LDROW(g + 3, 2);
            // xp taps 0..7 for the 10th MFMA (window base = core-(1,1))
            short8 bx = *(const short8*)(comb + ((g + 1) * TW + (m2 + 1)) * PIT + 32);
            float4v acc = z4;
            __builtin_amdgcn_s_setprio(1);
            acc = __builtin_amdgcn_mfma_f32_16x16x32_bf16(wtnr[0], Ta0, acc, 0, 0, 0);
            acc = __builtin_amdgcn_mfma_f32_16x16x32_bf16(wtnr[1], Ta1, acc, 0, 0, 0);
            acc = __builtin_amdgcn_mfma_f32_16x16x32_bf16(wtnr[2], Ta2, acc, 0, 0, 0);
            acc = __builtin_amdgcn_mfma_f32_16x16x32_bf16(wtnr[3], Tb0, acc, 0, 0, 0);
            acc = __builtin_amdgcn_mfma_f32_16x16x32_bf16(wtnr[4], Tb1, acc, 0, 0, 0);
            acc = __builtin_amdgcn_mfma_f32_16x16x32_bf16(wtnr[5], Tb2, acc, 0, 0, 0);
            acc = __builtin_amdgcn_mfma_f32_16x16x32_bf16(wtnr[6], Tc0, acc, 0, 0, 0);
            acc = __builtin_amdgcn_mfma_f32_16x16x32_bf16(wtnr[7], Tc1, acc, 0, 0, 0);
            acc = __builtin_amdgcn_mfma_f32_16x16x32_bf16(wtnr[8], Tc2, acc, 0, 0, 0);
            acc = __builtin_amdgcn_mfma_f32_16x16x32_bf16(wtxr,   bx,  acc, 0, 0, 0);
            __builtin_amdgcn_s_setprio(0);
            int gy = gy0 + g;
            const size_t pix = pb + gy * 256 + gx0 + m2;
            const ushort_t* cpx = comb + ((g + 2) * TW + (m2 + 2)) * PIT;
            // tap 8 = x[core+(1,1)] = tap0 (ch32) of window based at (g+3,m2+3)
            float x8c = bu2f(comb[((g + 3) * TW + (m2 + 3)) * PIT + 32]);
            uint2 su = *(const uint2*)(cpx + 16 + och);        // state och..+3
            uint2 du = *(const uint2*)(cpx + och);             // delta
            float sold[4] = { lo2f(su.x), hi2f(su.x), lo2f(su.y), hi2f(su.y) };
            float dvv[4]  = { lo2f(du.x), hi2f(du.x), lo2f(du.y), hi2f(du.y) };
            float sn[4];
#pragma unroll
            for (int r = 0; r < 4; ++r) {
                float tl  = acc[r] + tb4[r] + x8c * wtx84[r];
                float e   = __expf(-tl);
                float bta = __builtin_amdgcn_rcpf(1.f + e);
                bta = __builtin_amdgcn_fmed3f(bta, 0.01f, 0.99f);
                sn[r] = dvv[r] + bta * (sold[r] - dvv[r]);
            }
            if (!last) {
                uint2 o;
                o.x = pack2(sn[0], sn[1]); o.y = pack2(sn[2], sn[3]);
                *(uint2*)(stOut + pix * 16 + och) = o;         // b64 store
            } else {
                // fused readout: channels spread over q -> butterfly on q bits
                float v = sn[0] * wr4[0] + sn[1] * wr4[1]
                        + sn[2] * wr4[2] + sn[3] * wr4[3];
                v += __shfl_xor(v, 16);
                v += __shfl_xor(v, 32);
                if (q == 0) {
                    float eo = __expf(-(v + br));
                    outg[pix] = __builtin_amdgcn_rcpf(1.f + eo);
                }
            }
            // rotate the row cache
            Ta0 = Tb0; Ta1 = Tb1; Ta2 = Tb2;
            Tb0 = Tc0; Tb1 = Tc1; Tb2 = Tc2;
        }
#undef LDROW
    }
}

// ---------------------------------------------------------------------------
extern "C" void kernel_launch(void* const* d_in, const int* in_sizes, int n_in,
                              void* d_out, int out_size, void* d_ws, size_t ws_size,
                              hipStream_t stream)
{
    const float* x          = (const float*)d_in[0];
    const float* w_perceive = (const float*)d_in[1];
    const float* b_perceive = (const float*)d_in[2];
    const float* w_up1      = (const float*)d_in[3];
    const float* b_up1      = (const float*)d_in[4];
    const float* w_up2      = (const float*)d_in[5];
    const float* b_up2      = (const float*)d_in[6];
    const float* w_tau      = (const float*)d_in[7];
    const float* b_tau_conv = (const float*)d_in[8];
    const float* b_tau      = (const float*)d_in[9];
    const float* w_read     = (const float*)d_in[10];
    const float* b_read     = (const float*)d_in[11];
    // d_in[12] = n_steps = 10 (host-known; hard-coded for graph capture)
    float* out = (float*)d_out;

    const size_t stateElems = (size_t)B_ * H_ * W_ * 16;     // 33,554,432 bf16
    const size_t xp8Elems   = (size_t)B_ * XPP * XPP * 8;    // 17,305,600 bf16

    // ws layout (~170 MB; tx tensor deleted)
    ushort_t* stA  = (ushort_t*)d_ws;
    ushort_t* stB  = stA + stateElems;
    ushort_t* xp8g = stB + stateElems;         // 34.6 MB
    ushort_t* wh1p = xp8g + xp8Elems;          // 2560
    ushort_t* wu2f = wh1p + 2560;              // 512
    ushort_t* wtxf = wu2f + 512;               // 512
    ushort_t* wtn  = wtxf + 512;               // 4608
    float*    scal = (float*)(wtn + 4608);     // 64 floats

    const size_t needBytes = (2 * stateElems + xp8Elems
                              + 2560 + 512 + 512 + 4608) * sizeof(ushort_t)
                           + 64 * sizeof(float);
    if (ws_size < needBytes) return;

    prep<<<dim3(1), dim3(256), 0, stream>>>(
        w_perceive, w_up1, b_up1, b_perceive, w_up2, w_tau,
        b_tau_conv, b_tau, wh1p, wu2f, wtxf, wtn, scal);
    precompute_xp8<<<dim3((B_ * XPP * XPP + 255) / 256), dim3(256), 0, stream>>>(
        x, xp8g);

    ushort_t* cur = stA;
    ushort_t* nxt = stB;
    for (int s = 0; s < 10; ++s) {
        nca_step<<<dim3(8, 16, 32), dim3(512), 0, stream>>>(
            cur, nxt, xp8g, wh1p, wu2f, wtxf, wtn, scal, b_up2,
            w_read, b_read, out, (s == 0) ? 1 : 0, (s == 9) ? 1 : 0);
        ushort_t* t = cur; cur = nxt; nxt = t;
    }
}

// Round 13
// 683.016 us; speedup vs baseline: 1.1904x; 1.0188x over previous
//
#include <hip/hip_runtime.h>
#include <hip/hip_bf16.h>
#include <math.h>

// LiquidNCA via bf16 MFMA, v3.17 = v3.16 (695.8 us best) + two isolated cuts:
//  (1) s_setprio REMOVED everywhere. Added in R3 bundled (never isolated);
//      T5/m190 evidence says setprio is ~0-to-negative on barrier-locked
//      lockstep multi-wave kernels (our exact structure): boosting the
//      MFMA-phase waves can starve the co-resident block's stage-A staging
//      waves, which is precisely the latency we need overlapped.
//  (2) stage-B abase strength-reduced to an incrementally-updated cell index
//      (addr += 3*TW+26, wrap += TW-34) -- deletes the per-iteration
//      pyc*TW+pxc mul chain. Stage C is fully unrolled, already folded.
// R12 lesson recorded: tile-widening delivered FETCH/conflict/LDS-instr
// predictions but ~no time -- kernel is latency-structure-bound (no pipe
// >62%); per-block 2-barrier convoy serializes {stage-A global latency ->
// stage-B MFMA -> stage-C MFMA} with only ~12 waves/CU of overlap.
// PRE-COMMITMENT: if this round is neutral, declare the structural plateau.
// v3.16 carried: 16x32 tile / 512 thr / 8 waves (20x36 halo comb, 57600 B,
// 2 blk/CU), RNE cvt_pk pack, fmed3 clamp, ZERO-SHUFFLE up2, stage-C
// tap-row register cache, stage-B tap-8 in 5th MFMA at K=24, interior fast
// path, incremental py/px, tau x via 10th stage-C MFMA, no tx tensor.
// Failed-and-reverted (do not retry): 2-step fusion (R6), stage-C global
// prefetch (R9), XCD swizzle (R5).
// Core concept (R14-verified): mfma(weights, pixels, acc) -> D[channel][pixel]
// (A/B lane layouts are identical), so each lane owns 1 pixel x 4 consecutive
// channels and every epilogue access is one aligned b64.

#define B_   32
#define H_   256
#define W_   256
#define PIT  40                // comb pitch in ushorts (80 B, 16B-aligned)
#define XPP  260               // xp8pad padded dim (base gy in [-2, 257])
#define TW   36                // comb width  (32 + 4 halo)
#define TH   20                // comb height (16 + 4 halo)

typedef unsigned short ushort_t;
typedef __attribute__((ext_vector_type(8))) short short8;
typedef __attribute__((ext_vector_type(4))) float float4v;

__device__ __forceinline__ unsigned fbits(float f) {
    union { float f; unsigned u; } v; v.f = f; return v.u;
}
__device__ __forceinline__ ushort_t f2bu(float f) {        // finite-only, RHU
    return (ushort_t)((fbits(f) + 0x8000u) >> 16);
}
__device__ __forceinline__ unsigned pack2(float lo, float hi) {  // RNE, 1 instr
    union { __hip_bfloat162 h; unsigned u; } v;
    v.h = __float22bfloat162_rn(make_float2(lo, hi));
    return v.u;
}
__device__ __forceinline__ float bu2f(ushort_t u) {
    union { unsigned i; float f; } v; v.i = ((unsigned)u) << 16; return v.f;
}
__device__ __forceinline__ float lo2f(unsigned u) {
    union { unsigned i; float f; } v; v.i = u << 16; return v.f;
}
__device__ __forceinline__ float hi2f(unsigned u) {
    union { unsigned i; float f; } v; v.i = u & 0xFFFF0000u; return v.f;
}

// ---------------------------------------------------------------------------
// prep: UNCHANGED from v3.12/v3.15.
__global__ void prep(
    const float* __restrict__ wp,   // [32][17][9]
    const float* __restrict__ wu1,  // [16][32]
    const float* __restrict__ bu1,  // [16]
    const float* __restrict__ bp,   // [32]
    const float* __restrict__ wu2,  // [16][16]
    const float* __restrict__ wt,   // [16][33][9]
    const float* __restrict__ btc,  // [16]
    const float* __restrict__ bt,   // [16]
    ushort_t* __restrict__ wh1p,    // [5][64][8]  4 pairs + (tap8||x0..8)
    ushort_t* __restrict__ wu2f,    // [64][8]
    ushort_t* __restrict__ wtxf,    // [64][8]  tau x-taps, K: 0..7 used
    ushort_t* __restrict__ wtn,     // [9][64][8]
    float* __restrict__ scal)       // [64] beff | wxh8 | tb | wtx8
{
    __shared__ float Weff[16 * 153];   // [n][c(0..16)][t]
    const int tid = threadIdx.x;

    for (int i = tid; i < 16 * 153; i += 256) {
        int j = i / 153, rem = i % 153, c = rem / 9, t = rem % 9;
        float s = 0.f;
        for (int o = 0; o < 32; ++o)
            s += wu1[j * 32 + o] * wp[o * 153 + c * 9 + t];
        Weff[i] = s;
    }
    if (tid < 16) {
        float s = bu1[tid];
        for (int o = 0; o < 32; ++o) s += wu1[tid * 32 + o] * bp[o];
        scal[tid] = s;                          // beff
    }
    if (tid < 16) scal[32 + tid] = btc[tid] + bt[tid];   // tau bias
    if (tid < 16) scal[48 + tid] = wt[tid * 297 + 8];    // tau tap-8 x weight
    __syncthreads();

    if (tid < 16) scal[16 + tid] = Weff[tid * 153 + 8];   // wxh8 (c=0, tap8)

    // pairs ii=0..3: K = [state@tap2ii (k0..15) || state@tap2ii+1 (k16..31)]
    for (int i = tid; i < 4 * 64 * 8; i += 256) {
        int ii = i >> 9, lane = (i >> 3) & 63, j = i & 7;
        int n = lane & 15, kk = ((lane >> 4) << 3) + j;
        int tap = 2 * ii + (kk >> 4), ch = kk & 15;
        wh1p[i] = f2bu(Weff[n * 153 + (ch + 1) * 9 + tap]);
    }
    // 5th: k<16 -> state@tap8; k=16..23 -> x@tap(k-16); k==24 -> x@tap8; else 0
    for (int i = tid; i < 512; i += 256) {
        int lane = i >> 3, j = i & 7;
        int n = lane & 15, k = ((lane >> 4) << 3) + j;
        float v = 0.f;
        if (k < 16)       v = Weff[n * 153 + (k + 1) * 9 + 8];
        else if (k < 24)  v = Weff[n * 153 + (k - 16)];      // c=0, tap k-16
        else if (k == 24) v = Weff[n * 153 + 8];             // c=0, tap 8
        wh1p[2048 + i] = f2bu(v);
    }
    // wu2f (zero-shuffle remap): k = 8a+b -> (b<4) ? wu2[n][4a+b] : 0
    for (int i = tid; i < 512; i += 256) {
        int lane = i >> 3, j = i & 7;
        int n = lane & 15, k = ((lane >> 4) << 3) + j;
        int a = k >> 3, b = k & 7;
        wu2f[i] = (b < 4) ? f2bu(wu2[n * 16 + 4 * a + b]) : (ushort_t)0;
    }
    // wtxf: tau x-tap weights wt[n][0][t], K-slot t = tap (0..7), else 0
    for (int i = tid; i < 512; i += 256) {
        int lane = i >> 3, j = i & 7;
        int n = lane & 15, k = ((lane >> 4) << 3) + j;
        wtxf[i] = (k < 8) ? f2bu(wt[n * 297 + k]) : (ushort_t)0;
    }
    // wtn: A = [delta(16) || state(16)] weights for tau
    for (int i = tid; i < 9 * 64 * 8; i += 256) {
        int t = i / 512, lane = (i / 8) % 64, j = i % 8;
        int n = lane & 15, k = ((lane >> 4) << 3) + j;
        int c = (k < 16) ? (17 + k) : (k - 15);
        wtn[i] = f2bu(wt[n * 297 + c * 9 + t]);
    }
}

// ---------------------------------------------------------------------------
// xp8pad[b][by][bx][8] = bf16 x at taps 0..7 of the 3x3 window based at
// global (by-2, bx-2); out-of-image taps are zero. tap0 = own x.
__global__ __launch_bounds__(256) void precompute_xp8(
    const float* __restrict__ x,     // [B][H][W] fp32
    ushort_t* __restrict__ xp8)      // [B][XPP][XPP][8] bf16
{
    int idx = blockIdx.x * 256 + threadIdx.x;
    if (idx >= B_ * XPP * XPP) return;
    int b  = idx / (XPP * XPP), rem = idx - b * (XPP * XPP);
    int by = rem / XPP, bx = rem - by * XPP;
    int gy = by - 2, gx = bx - 2;                 // window base in image coords
    const float* xb = x + (size_t)b * 65536;
    short8 v;
#pragma unroll
    for (int t = 0; t < 8; ++t) {
        int yy = gy + t / 3, xx = gx + t % 3;
        bool in = ((unsigned)yy < 256u) & ((unsigned)xx < 256u);
        v[t] = in ? (short)f2bu(xb[yy * 256 + xx]) : (short)0;
    }
    *(short8*)(xp8 + (size_t)idx * 8) = v;
}

// ---------------------------------------------------------------------------
__global__ __launch_bounds__(512) void nca_step(
    const ushort_t* __restrict__ stIn,   // [B][H][W][16] bf16 (unused if first)
    ushort_t* __restrict__ stOut,        // [B][H][W][16] bf16 (unused if last)
    const ushort_t* __restrict__ xp8g,   // [B][XPP][XPP][8] bf16
    const ushort_t* __restrict__ wh1p,
    const ushort_t* __restrict__ wu2f,
    const ushort_t* __restrict__ wtxf,
    const ushort_t* __restrict__ wtn,
    const float* __restrict__ scal,      // [64] beff | wxh8 | tb | wtx8
    const float* __restrict__ bu2G,
    const float* __restrict__ wrd,       // w_read [16]
    const float* __restrict__ brd,       // b_read [1]
    float* __restrict__ outg,            // [B][H][W] fp32 (used if last)
    int first, int last)
{
    __shared__ ushort_t comb[TH * TW * PIT]; // 20x36 halo-4; 57600 B -> 2 blk/CU

    const int tid  = threadIdx.x;
    const int w    = tid >> 6, lane = tid & 63;
    const int m    = lane & 15, q = lane >> 4;
    const int och  = q * 4;              // base out-channel of this lane's D rows
    const int gx0  = blockIdx.x * 32, gy0 = blockIdx.y * 16;
    const size_t pb = (size_t)blockIdx.z * 65536;
    const size_t xpb = (size_t)blockIdx.z * (XPP * XPP);
    const short8 z8 = {0, 0, 0, 0, 0, 0, 0, 0};
    const float4v z4 = {0.f, 0.f, 0.f, 0.f};

    // all staged rows / h1 pixels / delta pixels in-image for this block?
    const bool interior = (blockIdx.x >= 1) & (blockIdx.x <= 6)
                        & (blockIdx.y >= 1) & (blockIdx.y <= 14);

    // per-wave weight fragments (used as MFMA *A* operands)
    short8 wh1r[5], wtnr[9];
#pragma unroll
    for (int i = 0; i < 5; ++i) wh1r[i] = *(const short8*)(wh1p + (i * 64 + lane) * 8);
#pragma unroll
    for (int t = 0; t < 9; ++t) wtnr[t] = *(const short8*)(wtn + (t * 64 + lane) * 8);
    const short8 wu2r = *(const short8*)(wu2f + lane * 8);
    const short8 wtxr = *(const short8*)(wtxf + lane * 8);

    // per-lane channel-quad biases (channels och..och+3)
    float4v beff4, bu24, wr4, tb4, wtx84;
#pragma unroll
    for (int r = 0; r < 4; ++r) {
        beff4[r] = scal[och + r];
        tb4[r]   = scal[32 + och + r];
        wtx84[r] = scal[48 + och + r];
        bu24[r]  = bu2G[och + r];
        wr4[r]   = wrd[och + r];
    }
    const float br = brd[0];

    // per-lane paired-tap B-read offsets (tap = 2*ii + (q>>1)), grid width TW
    const int sel = q >> 1;
    int offp[4];
#pragma unroll
    for (int ii = 0; ii < 4; ++ii) {
        int tA = 2 * ii, tB = 2 * ii + 1;
        int oA = ((tA / 3) * TW + (tA % 3)) * PIT;
        int oB = ((tB / 3) * TW + (tB % 3)) * PIT;
        offp[ii] = sel ? oB : oA;
    }
    const int chOff = 16 + (q & 1) * 8;
    const int t8off = (2 * TW + 2) * PIT;
    // 5th-MFMA B offsets: q=0/1 -> state@tap8 (k0..15); q=2 -> x taps0..7
    // (k16..23); q=3 -> chunk4 of row (py+2,px+2): j=0 = x@tap8 (k24).
    const int off5  = (q == 0) ? (t8off + 16) : (q == 1) ? (t8off + 24)
                    : (q == 2) ? 32 : (t8off + 32);

    // ---- stage A: stage state ch16..31 + xpatch8 ch32..39 (coalesced) ------
    if (interior & (first == 0)) {
        for (int p = tid; p < TH * TW; p += 512) {
            int ry = p / TW, rx = p - ry * TW;
            ushort_t* row = comb + p * PIT;
            const ushort_t* sp = stIn
                + (pb + (size_t)(gy0 + ry - 2) * 256 + (gx0 + rx - 2)) * 16;
            *(short8*)(row + 16) = *(const short8*)(sp);
            *(short8*)(row + 24) = *(const short8*)(sp + 8);
            *(short8*)(row + 32) = *(const short8*)(
                xp8g + (xpb + (size_t)(gy0 + ry) * XPP + (gx0 + rx)) * 8);
        }
    } else {
        for (int p = tid; p < TH * TW; p += 512) {
            int ry = p / TW, rx = p - ry * TW;
            int gy = gy0 + ry - 2, gx = gx0 + rx - 2;
            ushort_t* row = comb + p * PIT;
            bool in = ((unsigned)gy < 256u) & ((unsigned)gx < 256u);
            if (in && !first) {
                const ushort_t* sp = stIn + (pb + gy * 256 + gx) * 16;
                *(short8*)(row + 16) = *(const short8*)(sp);
                *(short8*)(row + 24) = *(const short8*)(sp + 8);
            } else {
                *(short8*)(row + 16) = z8; *(short8*)(row + 24) = z8;
            }
            *(short8*)(row + 32) = *(const short8*)(
                xp8g + (xpb + (size_t)(gy0 + ry) * XPP + (gx0 + rx)) * 8);
        }
    }
    __syncthreads();

    // ---- stage B: 5-MFMA h1 conv (D[ch][pix]) -> up2 -> inline delta -------
    // delta region 18x34 = 612 pixels -> 39 groups of 16; wave w takes
    // groups w, w+8, ... (waves 0-6: 5 iters, wave 7: 4). Cell index addr =
    // py*TW+px maintained incrementally (no per-iter mul).
    {
        int raw = w * 16 + m;                    // pixel index for i=0
        int py = raw / 34, px = raw - (raw / 34) * 34;
        int addr = py * TW + px;                 // comb cell index
        for (int i = 0; i < 5; ++i) {
            int g = w + 8 * i; if (g >= 39) break;
            bool vld = raw < 612;
            int addrc = vld ? addr : (17 * TW + 33);
            const ushort_t* abase = comb + addrc * PIT;
            float4v acc = z4;
#pragma unroll
            for (int ii = 0; ii < 4; ++ii) {
                short8 b = *(const short8*)(abase + offp[ii] + chOff);
                acc = __builtin_amdgcn_mfma_f32_16x16x32_bf16(wh1r[ii], b, acc, 0, 0, 0);
            }
            {   // 5th: [state@tap8 || x@taps0..7 || x@tap8 || 0]
                short8 b = *(const short8*)(abase + off5);
                acc = __builtin_amdgcn_mfma_f32_16x16x32_bf16(wh1r[4], b, acc, 0, 0, 0);
            }
            // epilogue: this lane owns its pixel, channels och..och+3
            uint2 hv;
            hv.x = pack2(fmaxf(acc[0] + beff4[0], 0.f),
                         fmaxf(acc[1] + beff4[1], 0.f));
            hv.y = pack2(fmaxf(acc[2] + beff4[2], 0.f),
                         fmaxf(acc[3] + beff4[3], 0.f));
            // ZERO-SHUFFLE up2: lane (m,q) supplies B k-slots 8q..8q+7; wu2f
            // places channel 4q+jj at k-slot 8q+jj (jj<4) and 0 at jj>=4, so
            // this lane's own hv IS its B-fragment. No bpermute.
            union { unsigned u4[4]; short8 s8; } bb;
            bb.u4[0] = hv.x; bb.u4[1] = hv.y; bb.u4[2] = 0u; bb.u4[3] = 0u;
            float4v d = __builtin_amdgcn_mfma_f32_16x16x32_bf16(wu2r, bb.s8, z4, 0, 0, 0);
            // delta: one b64 write into comb ch0..15 at cell (py+1, px+1)
            uint2 dv;
            dv.x = pack2(d[0] + bu24[0], d[1] + bu24[1]);
            dv.y = pack2(d[2] + bu24[2], d[3] + bu24[3]);
            if (!interior) {
                int gy = gy0 - 1 + (vld ? py : 17);
                int gx = gx0 - 1 + (vld ? px : 33);
                bool im = ((unsigned)gy < 256u) & ((unsigned)gx < 256u);
                if (!im) { dv.x = 0u; dv.y = 0u; }   // ref zero-pads outside
            }
            if (vld)
                *(uint2*)(comb + (addrc + TW + 1) * PIT + och) = dv;
            // increment pixel index by 128: +3 rows +26 cols (mod 34)
            raw += 128; px += 26; py += 3; addr += 3 * TW + 26;
            if (px >= 34) { px -= 34; py += 1; addr += TW - 34; }
        }
    }
    __syncthreads();

    // ---- stage C: tau conv (D[ch][pix], K=32 [delta||state]) + x via MFMA --
    // 32 groups (16 rows x 2 col-halves) / 8 waves = 4 each, balanced.
    // Wave w: col-half w&1 (cols m2 = (w&1)*16 + m), rows (w>>1)*4 + i.
    // Tap-row register cache: Ta = row g+1, Tb = row g+2 (dx = 0..2, chunk q).
    {
        const int m2 = ((w & 1) << 4) + m;
        const int g0 = (w >> 1) * 4;
#define LDROW(r, dx) (*(const short8*)(comb + (((r) * TW) + (m2 + 1 + (dx))) * PIT + q * 8))
        short8 Ta0 = LDROW(g0 + 1, 0), Ta1 = LDROW(g0 + 1, 1), Ta2 = LDROW(g0 + 1, 2);
        short8 Tb0 = LDROW(g0 + 2, 0), Tb1 = LDROW(g0 + 2, 1), Tb2 = LDROW(g0 + 2, 2);
#pragma unroll
        for (int i = 0; i < 4; ++i) {
            int g = g0 + i;                      // core row; pixel col = m2
            short8 Tc0 = LDROW(g + 3, 0), Tc1 = LDROW(g + 3, 1), Tc2 = LDROW(g + 3, 2);
            // xp taps 0..7 for the 10th MFMA (window base = core-(1,1))
            short8 bx = *(const short8*)(comb + ((g + 1) * TW + (m2 + 1)) * PIT + 32);
            float4v acc = z4;
            acc = __builtin_amdgcn_mfma_f32_16x16x32_bf16(wtnr[0], Ta0, acc, 0, 0, 0);
            acc = __builtin_amdgcn_mfma_f32_16x16x32_bf16(wtnr[1], Ta1, acc, 0, 0, 0);
            acc = __builtin_amdgcn_mfma_f32_16x16x32_bf16(wtnr[2], Ta2, acc, 0, 0, 0);
            acc = __builtin_amdgcn_mfma_f32_16x16x32_bf16(wtnr[3], Tb0, acc, 0, 0, 0);
            acc = __builtin_amdgcn_mfma_f32_16x16x32_bf16(wtnr[4], Tb1, acc, 0, 0, 0);
            acc = __builtin_amdgcn_mfma_f32_16x16x32_bf16(wtnr[5], Tb2, acc, 0, 0, 0);
            acc = __builtin_amdgcn_mfma_f32_16x16x32_bf16(wtnr[6], Tc0, acc, 0, 0, 0);
            acc = __builtin_amdgcn_mfma_f32_16x16x32_bf16(wtnr[7], Tc1, acc, 0, 0, 0);
            acc = __builtin_amdgcn_mfma_f32_16x16x32_bf16(wtnr[8], Tc2, acc, 0, 0, 0);
            acc = __builtin_amdgcn_mfma_f32_16x16x32_bf16(wtxr,   bx,  acc, 0, 0, 0);
            int gy = gy0 + g;
            const size_t pix = pb + gy * 256 + gx0 + m2;
            const ushort_t* cpx = comb + ((g + 2) * TW + (m2 + 2)) * PIT;
            // tap 8 = x[core+(1,1)] = tap0 (ch32) of window based at (g+3,m2+3)
            float x8c = bu2f(comb[((g + 3) * TW + (m2 + 3)) * PIT + 32]);
            uint2 su = *(const uint2*)(cpx + 16 + och);        // state och..+3
            uint2 du = *(const uint2*)(cpx + och);             // delta
            float sold[4] = { lo2f(su.x), hi2f(su.x), lo2f(su.y), hi2f(su.y) };
            float dvv[4]  = { lo2f(du.x), hi2f(du.x), lo2f(du.y), hi2f(du.y) };
            float sn[4];
#pragma unroll
            for (int r = 0; r < 4; ++r) {
                float tl  = acc[r] + tb4[r] + x8c * wtx84[r];
                float e   = __expf(-tl);
                float bta = __builtin_amdgcn_rcpf(1.f + e);
                bta = __builtin_amdgcn_fmed3f(bta, 0.01f, 0.99f);
                sn[r] = dvv[r] + bta * (sold[r] - dvv[r]);
            }
            if (!last) {
                uint2 o;
                o.x = pack2(sn[0], sn[1]); o.y = pack2(sn[2], sn[3]);
                *(uint2*)(stOut + pix * 16 + och) = o;         // b64 store
            } else {
                // fused readout: channels spread over q -> butterfly on q bits
                float v = sn[0] * wr4[0] + sn[1] * wr4[1]
                        + sn[2] * wr4[2] + sn[3] * wr4[3];
                v += __shfl_xor(v, 16);
                v += __shfl_xor(v, 32);
                if (q == 0) {
                    float eo = __expf(-(v + br));
                    outg[pix] = __builtin_amdgcn_rcpf(1.f + eo);
                }
            }
            // rotate the row cache
            Ta0 = Tb0; Ta1 = Tb1; Ta2 = Tb2;
            Tb0 = Tc0; Tb1 = Tc1; Tb2 = Tc2;
        }
#undef LDROW
    }
}

// ---------------------------------------------------------------------------
extern "C" void kernel_launch(void* const* d_in, const int* in_sizes, int n_in,
                              void* d_out, int out_size, void* d_ws, size_t ws_size,
                              hipStream_t stream)
{
    const float* x          = (const float*)d_in[0];
    const float* w_perceive = (const float*)d_in[1];
    const float* b_perceive = (const float*)d_in[2];
    const float* w_up1      = (const float*)d_in[3];
    const float* b_up1      = (const float*)d_in[4];
    const float* w_up2      = (const float*)d_in[5];
    const float* b_up2      = (const float*)d_in[6];
    const float* w_tau      = (const float*)d_in[7];
    const float* b_tau_conv = (const float*)d_in[8];
    const float* b_tau      = (const float*)d_in[9];
    const float* w_read     = (const float*)d_in[10];
    const float* b_read     = (const float*)d_in[11];
    // d_in[12] = n_steps = 10 (host-known; hard-coded for graph capture)
    float* out = (float*)d_out;

    const size_t stateElems = (size_t)B_ * H_ * W_ * 16;     // 33,554,432 bf16
    const size_t xp8Elems   = (size_t)B_ * XPP * XPP * 8;    // 17,305,600 bf16

    // ws layout (~170 MB; tx tensor deleted)
    ushort_t* stA  = (ushort_t*)d_ws;
    ushort_t* stB  = stA + stateElems;
    ushort_t* xp8g = stB + stateElems;         // 34.6 MB
    ushort_t* wh1p = xp8g + xp8Elems;          // 2560
    ushort_t* wu2f = wh1p + 2560;              // 512
    ushort_t* wtxf = wu2f + 512;               // 512
    ushort_t* wtn  = wtxf + 512;               // 4608
    float*    scal = (float*)(wtn + 4608);     // 64 floats

    const size_t needBytes = (2 * stateElems + xp8Elems
                              + 2560 + 512 + 512 + 4608) * sizeof(ushort_t)
                           + 64 * sizeof(float);
    if (ws_size < needBytes) return;

    prep<<<dim3(1), dim3(256), 0, stream>>>(
        w_perceive, w_up1, b_up1, b_perceive, w_up2, w_tau,
        b_tau_conv, b_tau, wh1p, wu2f, wtxf, wtn, scal);
    precompute_xp8<<<dim3((B_ * XPP * XPP + 255) / 256), dim3(256), 0, stream>>>(
        x, xp8g);

    ushort_t* cur = stA;
    ushort_t* nxt = stB;
    for (int s = 0; s < 10; ++s) {
        nca_step<<<dim3(8, 16, 32), dim3(512), 0, stream>>>(
            cur, nxt, xp8g, wh1p, wu2f, wtxf, wtn, scal, b_up2,
            w_read, b_read, out, (s == 0) ? 1 : 0, (s == 9) ? 1 : 0);
        ushort_t* t = cur; cur = nxt; nxt = t;
    }
}